// Round 1
// baseline (1667.539 us; speedup 1.0000x reference)
//
#include <hip/hip_runtime.h>

#define NEGS 0.01f
#define BNEPS 1e-5f

// ---------------------------------------------------------------------------
// Generic fp32 tiled GEMM: C[M,N] = A[M,K] @ B[K,N], optional fused epilogue.
// EPI 0: none; 1: +bias, leaky-relu, batchnorm(eval); 2: +bias only.
// 256 threads, 16x16 thread grid, each thread TM x TN outputs.
// ---------------------------------------------------------------------------
template<int BM, int BN, int BK, int TM, int TN, int EPI>
__global__ __launch_bounds__(256) void gemm_f32(
    const float* __restrict__ A, const float* __restrict__ B, float* __restrict__ C,
    int M, int N, int K,
    const float* __restrict__ bias, const float* __restrict__ bng,
    const float* __restrict__ bnb, const float* __restrict__ bnrm,
    const float* __restrict__ bnrv)
{
    __shared__ float As[BM][BK + 1];
    __shared__ float Bs[BK][BN];
    const int bm = blockIdx.y * BM, bn = blockIdx.x * BN;
    const int tx = threadIdx.x & 15, ty = threadIdx.x >> 4;

    float acc[TM][TN];
#pragma unroll
    for (int i = 0; i < TM; ++i)
#pragma unroll
        for (int j = 0; j < TN; ++j) acc[i][j] = 0.f;

    for (int k0 = 0; k0 < K; k0 += BK) {
        for (int i = threadIdx.x; i < BM * BK; i += 256) {
            int m = i / BK, kk = i % BK;
            int gm = bm + m, gk = k0 + kk;
            As[m][kk] = (gm < M && gk < K) ? A[(long)gm * K + gk] : 0.f;
        }
        for (int i = threadIdx.x; i < BK * BN; i += 256) {
            int kk = i / BN, n = i % BN;
            int gk = k0 + kk, gn = bn + n;
            Bs[kk][n] = (gk < K && gn < N) ? B[(long)gk * N + gn] : 0.f;
        }
        __syncthreads();
#pragma unroll
        for (int kk = 0; kk < BK; ++kk) {
            float a[TM], b[TN];
#pragma unroll
            for (int i = 0; i < TM; ++i) a[i] = As[ty * TM + i][kk];
#pragma unroll
            for (int j = 0; j < TN; ++j) b[j] = Bs[kk][tx + j * 16];
#pragma unroll
            for (int i = 0; i < TM; ++i)
#pragma unroll
                for (int j = 0; j < TN; ++j) acc[i][j] = fmaf(a[i], b[j], acc[i][j]);
        }
        __syncthreads();
    }

#pragma unroll
    for (int i = 0; i < TM; ++i) {
        int r = bm + ty * TM + i;
        if (r >= M) continue;
#pragma unroll
        for (int j = 0; j < TN; ++j) {
            int c = bn + tx + j * 16;
            if (c >= N) continue;
            float v = acc[i][j];
            if (EPI >= 1) v += bias[c];
            if (EPI == 1) {
                v = v >= 0.f ? v : NEGS * v;
                v = (v - bnrm[c]) * (1.0f / sqrtf(bnrv[c] + BNEPS)) * bng[c] + bnb[c];
            }
            C[(long)r * N + c] = v;
        }
    }
}

// ---------------------------------------------------------------------------
// Fused per-graph GCN finish (+deg, scatter-agg, self-loop, bias, lrelu)
// + TopK pooling (score, bitonic sort desc w/ tie->lower idx, tanh gate)
// + readout (max & mean) accumulated into z, + remap table for edge remap.
// One block (256 threads) per graph. NC nodes in, KK nodes kept.
// ---------------------------------------------------------------------------
template<int NC, int KK, bool FIRST, bool LAST, bool ACCUM>
__global__ __launch_bounds__(256) void gcn_topk(
    const float* __restrict__ h_pre,     // [G*NC,128]  = x @ W
    const int* __restrict__ srcA, const int* __restrict__ dstA,
    const float* __restrict__ emA,       // null when FIRST
    const float* __restrict__ bias, const float* __restrict__ p,
    float* __restrict__ x_new,           // [G*KK,128] (null when LAST)
    int* __restrict__ remap,             // [G*NC]     (null when LAST)
    float* __restrict__ z)               // [G,256]
{
    __shared__ float h_s[NC][128];
    __shared__ float agg_s[NC][128];
    __shared__ int   es[1024];
    __shared__ int   ed[1024];
    __shared__ float ee[1024];
    __shared__ float deg_s[NC], dis_s[NC], invd_s[NC];
    __shared__ float sc[128];
    __shared__ int   id[128];
    __shared__ float gate[KK];
    __shared__ float b_s[128], p_s[128];
    __shared__ float pnorm;

    const int g = blockIdx.x, tid = threadIdx.x;

    // ---- stage: h tile, edges, params; init agg/deg
    for (int i = tid; i < NC * 128; i += 256) {
        (&h_s[0][0])[i] = h_pre[(long)g * NC * 128 + i];
        (&agg_s[0][0])[i] = 0.f;
    }
    if (tid < 128) { b_s[tid] = bias[tid]; p_s[tid] = p[tid]; }
    for (int e = tid; e < 1024; e += 256) {
        int eg = g * 1024 + e;
        if (FIRST) { es[e] = srcA[eg] & 127; ed[e] = dstA[eg] & 127; ee[e] = 1.f; }
        else       { es[e] = srcA[eg];       ed[e] = dstA[eg];       ee[e] = emA[eg]; }
    }
    for (int i = tid; i < NC; i += 256) deg_s[i] = 1.f;   // self loop
    __syncthreads();

    // ---- ||p|| (wave 0)
    if (tid < 64) {
        float s = p_s[tid] * p_s[tid] + p_s[tid + 64] * p_s[tid + 64];
#pragma unroll
        for (int o = 32; o; o >>= 1) s += __shfl_xor(s, o, 64);
        if (tid == 0) pnorm = sqrtf(s);
    }
    // ---- degree
    for (int e = tid; e < 1024; e += 256) atomicAdd(&deg_s[ed[e]], ee[e]);
    __syncthreads();
    for (int i = tid; i < NC; i += 256) {
        float d = deg_s[i];
        dis_s[i] = 1.0f / sqrtf(d);
        invd_s[i] = 1.0f / d;
    }
    __syncthreads();

    // ---- edge scatter-aggregate: thread = feature, 2 edge groups
    {
        int f = tid & 127, grp = tid >> 7;
        int e0 = grp * 512;
        for (int e = e0; e < e0 + 512; ++e) {
            int s = es[e], d = ed[e];
            float c = dis_s[s] * dis_s[d] * ee[e];
            atomicAdd(&agg_s[d][f], h_s[s][f] * c);
        }
    }
    __syncthreads();

    // ---- act = lrelu(agg + h/deg + b), stored back into h_s
    for (int i = tid; i < NC * 128; i += 256) {
        int node = i >> 7, f = i & 127;
        float v = agg_s[node][f] + h_s[node][f] * invd_s[node] + b_s[f];
        (&h_s[0][0])[i] = v >= 0.f ? v : NEGS * v;
    }
    __syncthreads();

    // ---- scores: wave w handles nodes w, w+4, ... (lane = feature pair)
    {
        int w = tid >> 6, l = tid & 63;
        for (int i = w; i < NC; i += 4) {
            float s = h_s[i][l] * p_s[l] + h_s[i][l + 64] * p_s[l + 64];
#pragma unroll
            for (int o = 32; o; o >>= 1) s += __shfl_xor(s, o, 64);
            if (l == 0) { sc[i] = s / pnorm; id[i] = i; }
        }
    }
    if (tid >= NC && tid < 128) { sc[tid] = -__builtin_inff(); id[tid] = 0x7fffffff; }
    __syncthreads();

    // ---- bitonic sort (128), descending by score, ties -> lower index
    for (int size = 2; size <= 128; size <<= 1) {
        for (int stride = size >> 1; stride > 0; stride >>= 1) {
            if (tid < 64) {
                int i = 2 * stride * (tid / stride) + (tid % stride);
                int j = i + stride;
                float si_ = sc[i], sj_ = sc[j];
                int ii = id[i], ij = id[j];
                bool iFirst = (si_ > sj_) || (si_ == sj_ && ii < ij);
                bool descRegion = ((i & size) == 0);
                bool doSwap = descRegion ? !iFirst : iFirst;
                if (doSwap) { sc[i] = sj_; sc[j] = si_; id[i] = ij; id[j] = ii; }
            }
            __syncthreads();
        }
    }

    // ---- gates + remap init
    for (int j = tid; j < KK; j += 256) gate[j] = tanhf(sc[j]);
    if constexpr (!LAST) {
        for (int i = tid; i < NC; i += 256) remap[g * NC + i] = -1;
    }
    __syncthreads();
    if constexpr (!LAST) {
        for (int j = tid; j < KK; j += 256) remap[g * NC + id[j]] = j;
    }

    // ---- gather + gate + readout
    if (tid < 128) {
        int f = tid;
        float rmax = -__builtin_inff(), rsum = 0.f;
        for (int j = 0; j < KK; ++j) {
            float v = h_s[id[j]][f] * gate[j];
            if constexpr (!LAST) x_new[((long)g * KK + j) * 128 + f] = v;
            rmax = fmaxf(rmax, v);
            rsum += v;
        }
        float rmean = rsum / (float)KK;
        if constexpr (ACCUM) {
            z[g * 256 + f] += rmax;
            z[g * 256 + 128 + f] += rmean;
        } else {
            z[g * 256 + f] = rmax;
            z[g * 256 + 128 + f] = rmean;
        }
    }
}

// ---------------------------------------------------------------------------
// Edge remap after pooling: local indices in, local indices out; em masking
// exactly as reference (clamped-to-0 indices, em *= ok).
// ---------------------------------------------------------------------------
template<bool FIRST>
__global__ __launch_bounds__(256) void remap_edges(
    const int* __restrict__ srcA, const int* __restrict__ dstA,
    const float* __restrict__ emA,
    const int* __restrict__ remap, int n_cur,
    int* __restrict__ srcB, int* __restrict__ dstB, float* __restrict__ emB)
{
    int e = blockIdx.x * 256 + threadIdx.x;
    int g = e >> 10;
    int sl, dl; float m;
    if (FIRST) { sl = srcA[e] & 127; dl = dstA[e] & 127; m = 1.f; }
    else       { sl = srcA[e];       dl = dstA[e];       m = emA[e]; }
    int s2 = remap[g * n_cur + sl];
    int d2 = remap[g * n_cur + dl];
    bool ok = (s2 >= 0) && (d2 >= 0);
    srcB[e] = ok ? s2 : 0;
    dstB[e] = ok ? d2 : 0;
    emB[e] = ok ? m : 0.f;
}

// ---------------------------------------------------------------------------
// MLP tail per row: lin2 (1024->64) + lrelu + bn2, lin3 (64->2) + bias.
// One block per row.
// ---------------------------------------------------------------------------
__global__ __launch_bounds__(256) void mlp_tail(
    const float* __restrict__ t1,
    const float* __restrict__ W2, const float* __restrict__ b2v,
    const float* __restrict__ g2, const float* __restrict__ bb2,
    const float* __restrict__ rm2, const float* __restrict__ rv2,
    const float* __restrict__ W3, const float* __restrict__ b3v,
    float* __restrict__ out)
{
    __shared__ float t1s[1024];
    __shared__ float part[4][64];
    __shared__ float t2s[64];
    const int row = blockIdx.x, tid = threadIdx.x;

    for (int i = tid; i < 1024; i += 256) t1s[i] = t1[(long)row * 1024 + i];
    __syncthreads();

    int c = tid & 63, seg = tid >> 6;
    float s = 0.f;
    for (int k = seg * 256; k < seg * 256 + 256; ++k)
        s = fmaf(t1s[k], W2[k * 64 + c], s);
    part[seg][c] = s;
    __syncthreads();

    if (tid < 64) {
        float v = part[0][c] + part[1][c] + part[2][c] + part[3][c] + b2v[c];
        v = v >= 0.f ? v : NEGS * v;
        v = (v - rm2[c]) * (1.0f / sqrtf(rv2[c] + BNEPS)) * g2[c] + bb2[c];
        t2s[c] = v;
    }
    __syncthreads();

    if (tid < 128) {
        int cc = tid >> 6, k = tid & 63;
        float prod = t2s[k] * W3[k * 2 + cc];
#pragma unroll
        for (int o = 32; o; o >>= 1) prod += __shfl_xor(prod, o, 64);
        if (k == 0) out[row * 2 + cc] = prod + b3v[cc];
    }
}

// ---------------------------------------------------------------------------
extern "C" void kernel_launch(void* const* d_in, const int* in_sizes, int n_in,
                              void* d_out, int out_size, void* d_ws, size_t ws_size,
                              hipStream_t stream)
{
    const float* x    = (const float*)d_in[0];
    const int*   src  = (const int*)d_in[1];
    const int*   dst  = (const int*)d_in[2];
    const float* W1   = (const float*)d_in[4];
    const float* b1   = (const float*)d_in[5];
    const float* W2   = (const float*)d_in[6];
    const float* b2   = (const float*)d_in[7];
    const float* W3   = (const float*)d_in[8];
    const float* b3   = (const float*)d_in[9];
    const float* p1   = (const float*)d_in[10];
    const float* p2   = (const float*)d_in[11];
    const float* p3   = (const float*)d_in[12];
    const float* l1W  = (const float*)d_in[13];
    const float* l1b  = (const float*)d_in[14];
    const float* l2W  = (const float*)d_in[15];
    const float* l2b  = (const float*)d_in[16];
    const float* l3W  = (const float*)d_in[17];
    const float* l3b  = (const float*)d_in[18];
    const float* bn1g = (const float*)d_in[19];
    const float* bn1b = (const float*)d_in[20];
    const float* bn1rm= (const float*)d_in[21];
    const float* bn1rv= (const float*)d_in[22];
    const float* bn2g = (const float*)d_in[23];
    const float* bn2b = (const float*)d_in[24];
    const float* bn2rm= (const float*)d_in[25];
    const float* bn2rv= (const float*)d_in[26];
    float* out = (float*)d_out;

    // workspace layout (floats)
    float* ws = (float*)d_ws;
    size_t o = 0;
    float* h_pre = ws + o; o += 65536L * 128;        // 8,388,608
    float* x_cur = ws + o; o += 52736L * 128;        // 6,750,208
    float* z     = ws + o; o += 512L * 256;          // 131,072
    float* t1    = ws + o; o += 512L * 1024;         // 524,288
    int*   remap = (int*)(ws + o); o += 65536;       // node remap (reused)
    int*   eSA   = (int*)(ws + o); o += 524288;
    int*   eDA   = (int*)(ws + o); o += 524288;
    float* emA   = ws + o; o += 524288;
    int*   eSB   = (int*)(ws + o); o += 524288;
    int*   eDB   = (int*)(ws + o); o += 524288;
    float* emB   = ws + o; o += 524288;

    // ---- Layer 1: h = x @ W1  (M=65536, N=128, K=133)
    gemm_f32<64,128,16,4,8,0><<<dim3(1,1024), 256, 0, stream>>>(
        x, W1, h_pre, 65536, 128, 133, nullptr, nullptr, nullptr, nullptr, nullptr);
    gcn_topk<128,103,true,false,false><<<512, 256, 0, stream>>>(
        h_pre, src, dst, nullptr, b1, p1, x_cur, remap, z);
    remap_edges<true><<<2048, 256, 0, stream>>>(
        src, dst, nullptr, remap, 128, eSA, eDA, emA);

    // ---- Layer 2: h = x2 @ W2  (M=52736, N=128, K=128)
    gemm_f32<64,128,16,4,8,0><<<dim3(1,824), 256, 0, stream>>>(
        x_cur, W2, h_pre, 52736, 128, 128, nullptr, nullptr, nullptr, nullptr, nullptr);
    gcn_topk<103,83,false,false,true><<<512, 256, 0, stream>>>(
        h_pre, eSA, eDA, emA, b2, p2, x_cur, remap, z);
    remap_edges<false><<<2048, 256, 0, stream>>>(
        eSA, eDA, emA, remap, 103, eSB, eDB, emB);

    // ---- Layer 3: h = x3 @ W3  (M=42496, N=128, K=128)
    gemm_f32<64,128,16,4,8,0><<<dim3(1,664), 256, 0, stream>>>(
        x_cur, W3, h_pre, 42496, 128, 128, nullptr, nullptr, nullptr, nullptr, nullptr);
    gcn_topk<83,67,false,true,true><<<512, 256, 0, stream>>>(
        h_pre, eSB, eDB, emB, b3, p3, nullptr, nullptr, z);

    // ---- MLP head: t1 = bn1(lrelu(z @ lin1_W + b))  (M=512, N=1024, K=256)
    gemm_f32<16,128,16,1,8,1><<<dim3(8,32), 256, 0, stream>>>(
        z, l1W, t1, 512, 1024, 256, l1b, bn1g, bn1b, bn1rm, bn1rv);
    // ---- lin2 + bn2 + lin3
    mlp_tail<<<512, 256, 0, stream>>>(
        t1, l2W, l2b, bn2g, bn2b, bn2rm, bn2rv, l3W, l3b, out);
}

// Round 2
// 1141.322 us; speedup vs baseline: 1.4611x; 1.4611x over previous
//
#include <hip/hip_runtime.h>

#define NEGS 0.01f
#define BNEPS 1e-5f

// ---------------------------------------------------------------------------
// Generic fp32 tiled GEMM: C[M,N] = A[M,K] @ B[K,N], optional fused epilogue.
// EPI 0: none; 1: +bias, leaky-relu, batchnorm(eval).
// 256 threads, 16x16 thread grid, each thread TM x TN outputs.
// ---------------------------------------------------------------------------
template<int BM, int BN, int BK, int TM, int TN, int EPI>
__global__ __launch_bounds__(256) void gemm_f32(
    const float* __restrict__ A, const float* __restrict__ B, float* __restrict__ C,
    int M, int N, int K,
    const float* __restrict__ bias, const float* __restrict__ bng,
    const float* __restrict__ bnb, const float* __restrict__ bnrm,
    const float* __restrict__ bnrv)
{
    __shared__ float As[BM][BK + 1];
    __shared__ float Bs[BK][BN];
    const int bm = blockIdx.y * BM, bn = blockIdx.x * BN;
    const int tx = threadIdx.x & 15, ty = threadIdx.x >> 4;

    float acc[TM][TN];
#pragma unroll
    for (int i = 0; i < TM; ++i)
#pragma unroll
        for (int j = 0; j < TN; ++j) acc[i][j] = 0.f;

    for (int k0 = 0; k0 < K; k0 += BK) {
        for (int i = threadIdx.x; i < BM * BK; i += 256) {
            int m = i / BK, kk = i % BK;
            int gm = bm + m, gk = k0 + kk;
            As[m][kk] = (gm < M && gk < K) ? A[(long)gm * K + gk] : 0.f;
        }
        for (int i = threadIdx.x; i < BK * BN; i += 256) {
            int kk = i / BN, n = i % BN;
            int gk = k0 + kk, gn = bn + n;
            Bs[kk][n] = (gk < K && gn < N) ? B[(long)gk * N + gn] : 0.f;
        }
        __syncthreads();
#pragma unroll
        for (int kk = 0; kk < BK; ++kk) {
            float a[TM], b[TN];
#pragma unroll
            for (int i = 0; i < TM; ++i) a[i] = As[ty * TM + i][kk];
#pragma unroll
            for (int j = 0; j < TN; ++j) b[j] = Bs[kk][tx + j * 16];
#pragma unroll
            for (int i = 0; i < TM; ++i)
#pragma unroll
                for (int j = 0; j < TN; ++j) acc[i][j] = fmaf(a[i], b[j], acc[i][j]);
        }
        __syncthreads();
    }

#pragma unroll
    for (int i = 0; i < TM; ++i) {
        int r = bm + ty * TM + i;
        if (r >= M) continue;
#pragma unroll
        for (int j = 0; j < TN; ++j) {
            int c = bn + tx + j * 16;
            if (c >= N) continue;
            float v = acc[i][j];
            if (EPI >= 1) v += bias[c];
            if (EPI == 1) {
                v = v >= 0.f ? v : NEGS * v;
                v = (v - bnrm[c]) * (1.0f / sqrtf(bnrv[c] + BNEPS)) * bng[c] + bnb[c];
            }
            C[(long)r * N + c] = v;
        }
    }
}

// ---------------------------------------------------------------------------
// Fused per-graph GCN finish + TopK pooling + readout.
// 1024 threads per block (= 1024 edges per graph: one edge per thread held in
// registers). LDS ~151KB -> 1 block/CU but 16 waves -> 50% occupancy.
// ---------------------------------------------------------------------------
template<int NC, int KK, bool FIRST, bool LAST, bool ACCUM>
__global__ __launch_bounds__(1024, 4) void gcn_topk(
    const float* __restrict__ h_pre,     // [G*NC,128]  = x @ W
    const int* __restrict__ srcA, const int* __restrict__ dstA,
    const float* __restrict__ emA,       // null when FIRST
    const float* __restrict__ bias, const float* __restrict__ p,
    float* __restrict__ x_new,           // [G*KK,128] (null when LAST)
    int* __restrict__ remap,             // [G*NC]     (null when LAST)
    float* __restrict__ z)               // [G,256]
{
    __shared__ float h_s[NC][128];
    __shared__ float agg_s[NC][128];
    __shared__ float2 epk[1024];         // packed edge: (s | d<<16, coef)
    __shared__ float deg_s[NC], dis_s[NC], invd_s[NC];
    __shared__ float sc[128];
    __shared__ int   id[128];
    __shared__ float gate[KK];
    __shared__ float b_s[128], p_s[128];
    __shared__ float pnorm;
    __shared__ float pmax[8][128], psum[8][128];

    const int g = blockIdx.x, tid = threadIdx.x;

    // ---- stage h (float4) + zero agg + params
    {
        const float4* hp = (const float4*)(h_pre + (long)g * NC * 128);
        float4* h4 = (float4*)&h_s[0][0];
        float4* a4 = (float4*)&agg_s[0][0];
        float4 z4 = make_float4(0.f, 0.f, 0.f, 0.f);
        for (int i = tid; i < NC * 32; i += 1024) { h4[i] = hp[i]; a4[i] = z4; }
    }
    if (tid < 128) { b_s[tid] = bias[tid]; p_s[tid] = p[tid]; }

    // ---- one edge per thread, kept in registers
    int es_r, ed_r; float em_r;
    {
        int eg = g * 1024 + tid;
        if (FIRST) { es_r = srcA[eg] & 127; ed_r = dstA[eg] & 127; em_r = 1.f; }
        else       { es_r = srcA[eg];       ed_r = dstA[eg];       em_r = emA[eg]; }
    }
    for (int i = tid; i < NC; i += 1024) deg_s[i] = 1.f;   // self loop
    __syncthreads();

    // ---- ||p|| (wave 0) + degree atomics
    if (tid < 64) {
        float s = p_s[tid] * p_s[tid] + p_s[tid + 64] * p_s[tid + 64];
#pragma unroll
        for (int o = 32; o; o >>= 1) s += __shfl_xor(s, o, 64);
        if (tid == 0) pnorm = sqrtf(s);
    }
    atomicAdd(&deg_s[ed_r], em_r);
    __syncthreads();

    for (int i = tid; i < NC; i += 1024) {
        float d = deg_s[i];
        dis_s[i] = 1.0f / sqrtf(d);
        invd_s[i] = 1.0f / d;
    }
    __syncthreads();

    // ---- pack edge (indices + norm coef) into one 8B LDS slot
    epk[tid] = make_float2(__int_as_float(es_r | (ed_r << 16)),
                           dis_s[es_r] * dis_s[ed_r] * em_r);
    __syncthreads();

    // ---- edge scatter-aggregate: thread=(feature, edge-group of 128)
    {
        const int f = tid & 127, e0 = (tid >> 7) << 7;
#pragma unroll 4
        for (int e = e0; e < e0 + 128; ++e) {
            float2 pk = epk[e];
            if (pk.y != 0.f) {                   // wave-uniform skip of masked edges
                int sd = __float_as_int(pk.x);
                atomicAdd(&agg_s[sd >> 16][f], h_s[sd & 0xffff][f] * pk.y);
            }
        }
    }
    __syncthreads();

    // ---- act = lrelu(agg + h/deg + b), stored back into h_s
    for (int i = tid; i < NC * 128; i += 1024) {
        int node = i >> 7, f = i & 127;
        float v = (&agg_s[0][0])[i] + (&h_s[0][0])[i] * invd_s[node] + b_s[f];
        (&h_s[0][0])[i] = v >= 0.f ? v : NEGS * v;
    }
    __syncthreads();

    // ---- scores: wave w handles nodes w, w+16, ...
    {
        int w = tid >> 6, l = tid & 63;
        for (int i = w; i < NC; i += 16) {
            float s = h_s[i][l] * p_s[l] + h_s[i][l + 64] * p_s[l + 64];
#pragma unroll
            for (int o = 32; o; o >>= 1) s += __shfl_xor(s, o, 64);
            if (l == 0) { sc[i] = s / pnorm; id[i] = i; }
        }
    }
    if (tid >= NC && tid < 128) { sc[tid] = -__builtin_inff(); id[tid] = 0x7fffffff; }
    __syncthreads();

    // ---- bitonic sort (128), descending by score, ties -> lower index
    for (int size = 2; size <= 128; size <<= 1) {
        for (int stride = size >> 1; stride > 0; stride >>= 1) {
            if (tid < 64) {
                int i = 2 * stride * (tid / stride) + (tid % stride);
                int j = i + stride;
                float si_ = sc[i], sj_ = sc[j];
                int ii = id[i], ij = id[j];
                bool iFirst = (si_ > sj_) || (si_ == sj_ && ii < ij);
                bool descRegion = ((i & size) == 0);
                bool doSwap = descRegion ? !iFirst : iFirst;
                if (doSwap) { sc[i] = sj_; sc[j] = si_; id[i] = ij; id[j] = ii; }
            }
            __syncthreads();
        }
    }

    // ---- gates + remap
    for (int j = tid; j < KK; j += 1024) gate[j] = tanhf(sc[j]);
    if constexpr (!LAST) {
        for (int i = tid; i < NC; i += 1024) remap[g * NC + i] = -1;
    }
    __syncthreads();
    if constexpr (!LAST) {
        for (int j = tid; j < KK; j += 1024) remap[g * NC + id[j]] = j;
    }

    // ---- gather + gate + x_new write + partial readout (thread = (jj, f))
    {
        const int f = tid & 127, jj = tid >> 7;
        float rmx = -__builtin_inff(), rsm = 0.f;
        for (int j = jj; j < KK; j += 8) {
            float v = h_s[id[j]][f] * gate[j];
            if constexpr (!LAST) x_new[((long)g * KK + j) * 128 + f] = v;
            rmx = fmaxf(rmx, v);
            rsm += v;
        }
        pmax[jj][f] = rmx; psum[jj][f] = rsm;
    }
    __syncthreads();

    if (tid < 128) {
        float m = pmax[0][tid], s = psum[0][tid];
#pragma unroll
        for (int jj = 1; jj < 8; ++jj) { m = fmaxf(m, pmax[jj][tid]); s += psum[jj][tid]; }
        float mean = s / (float)KK;
        if constexpr (ACCUM) {
            z[g * 256 + tid] += m;
            z[g * 256 + 128 + tid] += mean;
        } else {
            z[g * 256 + tid] = m;
            z[g * 256 + 128 + tid] = mean;
        }
    }
}

// ---------------------------------------------------------------------------
// Edge remap after pooling (exactly as reference: clamped-to-0, em *= ok).
// ---------------------------------------------------------------------------
template<bool FIRST>
__global__ __launch_bounds__(256) void remap_edges(
    const int* __restrict__ srcA, const int* __restrict__ dstA,
    const float* __restrict__ emA,
    const int* __restrict__ remap, int n_cur,
    int* __restrict__ srcB, int* __restrict__ dstB, float* __restrict__ emB)
{
    int e = blockIdx.x * 256 + threadIdx.x;
    int g = e >> 10;
    int sl, dl; float m;
    if (FIRST) { sl = srcA[e] & 127; dl = dstA[e] & 127; m = 1.f; }
    else       { sl = srcA[e];       dl = dstA[e];       m = emA[e]; }
    int s2 = remap[g * n_cur + sl];
    int d2 = remap[g * n_cur + dl];
    bool ok = (s2 >= 0) && (d2 >= 0);
    srcB[e] = ok ? s2 : 0;
    dstB[e] = ok ? d2 : 0;
    emB[e] = ok ? m : 0.f;
}

// ---------------------------------------------------------------------------
// MLP tail per row: lin2 (1024->64) + lrelu + bn2, lin3 (64->2) + bias.
// ---------------------------------------------------------------------------
__global__ __launch_bounds__(256) void mlp_tail(
    const float* __restrict__ t1,
    const float* __restrict__ W2, const float* __restrict__ b2v,
    const float* __restrict__ g2, const float* __restrict__ bb2,
    const float* __restrict__ rm2, const float* __restrict__ rv2,
    const float* __restrict__ W3, const float* __restrict__ b3v,
    float* __restrict__ out)
{
    __shared__ float t1s[1024];
    __shared__ float part[4][64];
    __shared__ float t2s[64];
    const int row = blockIdx.x, tid = threadIdx.x;

    for (int i = tid; i < 1024; i += 256) t1s[i] = t1[(long)row * 1024 + i];
    __syncthreads();

    int c = tid & 63, seg = tid >> 6;
    float s = 0.f;
    for (int k = seg * 256; k < seg * 256 + 256; ++k)
        s = fmaf(t1s[k], W2[k * 64 + c], s);
    part[seg][c] = s;
    __syncthreads();

    if (tid < 64) {
        float v = part[0][c] + part[1][c] + part[2][c] + part[3][c] + b2v[c];
        v = v >= 0.f ? v : NEGS * v;
        v = (v - rm2[c]) * (1.0f / sqrtf(rv2[c] + BNEPS)) * g2[c] + bb2[c];
        t2s[c] = v;
    }
    __syncthreads();

    if (tid < 128) {
        int cc = tid >> 6, k = tid & 63;
        float prod = t2s[k] * W3[k * 2 + cc];
#pragma unroll
        for (int o = 32; o; o >>= 1) prod += __shfl_xor(prod, o, 64);
        if (k == 0) out[row * 2 + cc] = prod + b3v[cc];
    }
}

// ---------------------------------------------------------------------------
extern "C" void kernel_launch(void* const* d_in, const int* in_sizes, int n_in,
                              void* d_out, int out_size, void* d_ws, size_t ws_size,
                              hipStream_t stream)
{
    const float* x    = (const float*)d_in[0];
    const int*   src  = (const int*)d_in[1];
    const int*   dst  = (const int*)d_in[2];
    const float* W1   = (const float*)d_in[4];
    const float* b1   = (const float*)d_in[5];
    const float* W2   = (const float*)d_in[6];
    const float* b2   = (const float*)d_in[7];
    const float* W3   = (const float*)d_in[8];
    const float* b3   = (const float*)d_in[9];
    const float* p1   = (const float*)d_in[10];
    const float* p2   = (const float*)d_in[11];
    const float* p3   = (const float*)d_in[12];
    const float* l1W  = (const float*)d_in[13];
    const float* l1b  = (const float*)d_in[14];
    const float* l2W  = (const float*)d_in[15];
    const float* l2b  = (const float*)d_in[16];
    const float* l3W  = (const float*)d_in[17];
    const float* l3b  = (const float*)d_in[18];
    const float* bn1g = (const float*)d_in[19];
    const float* bn1b = (const float*)d_in[20];
    const float* bn1rm= (const float*)d_in[21];
    const float* bn1rv= (const float*)d_in[22];
    const float* bn2g = (const float*)d_in[23];
    const float* bn2b = (const float*)d_in[24];
    const float* bn2rm= (const float*)d_in[25];
    const float* bn2rv= (const float*)d_in[26];
    float* out = (float*)d_out;

    // workspace layout (floats)
    float* ws = (float*)d_ws;
    size_t o = 0;
    float* h_pre = ws + o; o += 65536L * 128;
    float* x_cur = ws + o; o += 52736L * 128;
    float* z     = ws + o; o += 512L * 256;
    float* t1    = ws + o; o += 512L * 1024;
    int*   remap = (int*)(ws + o); o += 65536;
    int*   eSA   = (int*)(ws + o); o += 524288;
    int*   eDA   = (int*)(ws + o); o += 524288;
    float* emA   = ws + o; o += 524288;
    int*   eSB   = (int*)(ws + o); o += 524288;
    int*   eDB   = (int*)(ws + o); o += 524288;
    float* emB   = ws + o; o += 524288;

    // ---- Layer 1: h = x @ W1  (M=65536, N=128, K=133)
    gemm_f32<64,128,16,4,8,0><<<dim3(1,1024), 256, 0, stream>>>(
        x, W1, h_pre, 65536, 128, 133, nullptr, nullptr, nullptr, nullptr, nullptr);
    gcn_topk<128,103,true,false,false><<<512, 1024, 0, stream>>>(
        h_pre, src, dst, nullptr, b1, p1, x_cur, remap, z);
    remap_edges<true><<<2048, 256, 0, stream>>>(
        src, dst, nullptr, remap, 128, eSA, eDA, emA);

    // ---- Layer 2: h = x2 @ W2  (M=52736, N=128, K=128)
    gemm_f32<64,128,16,4,8,0><<<dim3(1,824), 256, 0, stream>>>(
        x_cur, W2, h_pre, 52736, 128, 128, nullptr, nullptr, nullptr, nullptr, nullptr);
    gcn_topk<103,83,false,false,true><<<512, 1024, 0, stream>>>(
        h_pre, eSA, eDA, emA, b2, p2, x_cur, remap, z);
    remap_edges<false><<<2048, 256, 0, stream>>>(
        eSA, eDA, emA, remap, 103, eSB, eDB, emB);

    // ---- Layer 3: h = x3 @ W3  (M=42496, N=128, K=128)
    gemm_f32<64,128,16,4,8,0><<<dim3(1,664), 256, 0, stream>>>(
        x_cur, W3, h_pre, 42496, 128, 128, nullptr, nullptr, nullptr, nullptr, nullptr);
    gcn_topk<83,67,false,true,true><<<512, 1024, 0, stream>>>(
        h_pre, eSB, eDB, emB, b3, p3, nullptr, nullptr, z);

    // ---- MLP head: t1 = bn1(lrelu(z @ lin1_W + b))  (M=512, N=1024, K=256)
    gemm_f32<16,128,16,1,8,1><<<dim3(8,32), 256, 0, stream>>>(
        z, l1W, t1, 512, 1024, 256, l1b, bn1g, bn1b, bn1rm, bn1rv);
    // ---- lin2 + bn2 + lin3
    mlp_tail<<<512, 256, 0, stream>>>(
        t1, l2W, l2b, bn2g, bn2b, bn2rm, bn2rv, l3W, l3b, out);
}

// Round 4
// 421.853 us; speedup vs baseline: 3.9529x; 2.7055x over previous
//
#include <hip/hip_runtime.h>

#define NEGS 0.01f
#define BNEPS 1e-5f

// ---------------------------------------------------------------------------
// Generic fp32 tiled GEMM: C[M,N] = A[M,K] @ B[K,N], optional fused epilogue.
// EPI 0: none; 1: +bias, leaky-relu, batchnorm(eval).
// ---------------------------------------------------------------------------
template<int BM, int BN, int BK, int TM, int TN, int EPI>
__global__ __launch_bounds__(256) void gemm_f32(
    const float* __restrict__ A, const float* __restrict__ B, float* __restrict__ C,
    int M, int N, int K,
    const float* __restrict__ bias, const float* __restrict__ bng,
    const float* __restrict__ bnb, const float* __restrict__ bnrm,
    const float* __restrict__ bnrv)
{
    __shared__ float As[BM][BK + 1];
    __shared__ float Bs[BK][BN];
    const int bm = blockIdx.y * BM, bn = blockIdx.x * BN;
    const int tx = threadIdx.x & 15, ty = threadIdx.x >> 4;

    float acc[TM][TN];
#pragma unroll
    for (int i = 0; i < TM; ++i)
#pragma unroll
        for (int j = 0; j < TN; ++j) acc[i][j] = 0.f;

    for (int k0 = 0; k0 < K; k0 += BK) {
        for (int i = threadIdx.x; i < BM * BK; i += 256) {
            int m = i / BK, kk = i % BK;
            int gm = bm + m, gk = k0 + kk;
            As[m][kk] = (gm < M && gk < K) ? A[(long)gm * K + gk] : 0.f;
        }
        for (int i = threadIdx.x; i < BK * BN; i += 256) {
            int kk = i / BN, n = i % BN;
            int gk = k0 + kk, gn = bn + n;
            Bs[kk][n] = (gk < K && gn < N) ? B[(long)gk * N + gn] : 0.f;
        }
        __syncthreads();
#pragma unroll
        for (int kk = 0; kk < BK; ++kk) {
            float a[TM], b[TN];
#pragma unroll
            for (int i = 0; i < TM; ++i) a[i] = As[ty * TM + i][kk];
#pragma unroll
            for (int j = 0; j < TN; ++j) b[j] = Bs[kk][tx + j * 16];
#pragma unroll
            for (int i = 0; i < TM; ++i)
#pragma unroll
                for (int j = 0; j < TN; ++j) acc[i][j] = fmaf(a[i], b[j], acc[i][j]);
        }
        __syncthreads();
    }

#pragma unroll
    for (int i = 0; i < TM; ++i) {
        int r = bm + ty * TM + i;
        if (r >= M) continue;
#pragma unroll
        for (int j = 0; j < TN; ++j) {
            int c = bn + tx + j * 16;
            if (c >= N) continue;
            float v = acc[i][j];
            if (EPI >= 1) v += bias[c];
            if (EPI == 1) {
                v = v >= 0.f ? v : NEGS * v;
                v = (v - bnrm[c]) * (1.0f / sqrtf(bnrv[c] + BNEPS)) * bng[c] + bnb[c];
            }
            C[(long)r * N + c] = v;
        }
    }
}

// ---------------------------------------------------------------------------
// Fused per-graph: GCN finish (CSR build + atomic-free gather-aggregate +
// self-loop + bias + lrelu, written back IN PLACE to global h) + TopK
// (score, bitonic sort, tanh gate) + edge remap + gather/x_new + readout.
// 1024 threads; LDS ~77KB -> 2 blocks/CU -> all 512 graphs in ONE round.
// ---------------------------------------------------------------------------
template<int NC, int KK, bool FIRST, bool LAST, bool ACCUM>
__global__ __launch_bounds__(1024, 8) void gcn_topk(
    float* __restrict__ h,               // [G*NC,128] in: x@W ; out: activated
    const int* __restrict__ srcA, const int* __restrict__ dstA,
    const float* __restrict__ emA,       // null when FIRST
    const float* __restrict__ bias, const float* __restrict__ p,
    float* __restrict__ x_new,           // [G*KK,128]   (null when LAST)
    int* __restrict__ srcB, int* __restrict__ dstB, float* __restrict__ emB,
    float* __restrict__ z)               // [G,256]
{
    __shared__ float h_s[NC][128];       // input h staging (NC*512 B)
    __shared__ float2 csr[1024];         // (src_as_float, coef); later readout scratch
    __shared__ int   head[NC];           // histogram -> exclusive heads -> end offsets
    __shared__ float deg_s[NC], dis_s[NC], invd_s[NC];
    __shared__ float sc[128];
    __shared__ int   id[128];
    __shared__ float gate[KK];
    __shared__ float b_s[128], p_s[128];
    __shared__ int   remap_l[NC];
    __shared__ float pnorm;

    const int g = blockIdx.x, tid = threadIdx.x, lane = tid & 63;
    const float NINF = -__builtin_inff();

    // ---- edge in registers (one per thread)
    int es_r, ed_r; float em_r;
    {
        int eg = g * 1024 + tid;
        if (FIRST) { es_r = srcA[eg] & 127; ed_r = dstA[eg] & 127; em_r = 1.f; }
        else       { es_r = srcA[eg];       ed_r = dstA[eg];       em_r = emA[eg]; }
    }

    // ---- stage h tile (float4) + init
    {
        const float4* hp = (const float4*)(h + (long)g * NC * 128);
        float4* h4 = (float4*)&h_s[0][0];
        for (int i = tid; i < NC * 32; i += 1024) h4[i] = hp[i];
    }
    if (tid < 128) { b_s[tid] = bias[tid]; p_s[tid] = p[tid]; sc[tid] = 0.f; }
    for (int i = tid; i < NC; i += 1024) { deg_s[i] = 1.f; head[i] = 0; }
    __syncthreads();

    // ---- ||p|| (wave0) + degree/count histograms (masked edges excluded)
    if (tid < 64) {
        float s = p_s[tid] * p_s[tid] + p_s[tid + 64] * p_s[tid + 64];
#pragma unroll
        for (int o = 32; o; o >>= 1) s += __shfl_xor(s, o, 64);
        if (tid == 0) pnorm = sqrtf(s);
    }
    const bool live = FIRST || (em_r != 0.f);
    if (live) {
        atomicAdd(&deg_s[ed_r], em_r);
        atomicAdd(&head[ed_r], 1);
    }
    __syncthreads();

    for (int i = tid; i < NC; i += 1024) {
        float d = deg_s[i];
        dis_s[i] = 1.0f / sqrtf(d);
        invd_s[i] = 1.0f / d;
    }
    // ---- exclusive scan of counts -> head (wave0, shfl)
    if (tid < 64) {
        int c0 = head[tid];
        int c1 = (tid + 64 < NC) ? head[tid + 64] : 0;
        int s0 = c0, s1 = c1;
#pragma unroll
        for (int o = 1; o < 64; o <<= 1) { int t = __shfl_up(s0, o, 64); if (lane >= o) s0 += t; }
        int tot0 = __shfl(s0, 63, 64);
#pragma unroll
        for (int o = 1; o < 64; o <<= 1) { int t = __shfl_up(s1, o, 64); if (lane >= o) s1 += t; }
        s1 += tot0;
        head[tid] = s0 - c0;
        if (tid + 64 < NC) head[tid + 64] = s1 - c1;
    }
    __syncthreads();

    // ---- CSR place (head becomes per-node END offset afterwards)
    if (live) {
        int slot = atomicAdd(&head[ed_r], 1);
        csr[slot] = make_float2(__int_as_float(es_r), dis_s[es_r] * dis_s[ed_r] * em_r);
    }
    __syncthreads();

    // ---- atomic-free gather aggregate + act + in-place write-back + score
    {
        const int f = tid & 127, grp = tid >> 7;
        for (int nd = grp; nd < NC; nd += 8) {
            int kb = nd ? head[nd - 1] : 0;
            int ke = head[nd];
            float acc = 0.f;
            for (int k = kb; k < ke; ++k) {
                float2 rec = csr[k];
                acc += h_s[__float_as_int(rec.x)][f] * rec.y;
            }
            float v = acc + h_s[nd][f] * invd_s[nd] + b_s[f];
            v = v >= 0.f ? v : NEGS * v;
            h[((long)g * NC + nd) * 128 + f] = v;     // in-place act (global)
            float ps = v * p_s[f];
#pragma unroll
            for (int o = 32; o; o >>= 1) ps += __shfl_xor(ps, o, 64);
            if (lane == 0) atomicAdd(&sc[nd], ps);    // two half-sums per node
        }
    }
    __syncthreads();

    // ---- finalize scores
    if (tid < 128) {
        if (tid < NC) { sc[tid] = sc[tid] / pnorm; id[tid] = tid; }
        else          { sc[tid] = NINF; id[tid] = 0x7fffffff; }
    }
    __syncthreads();

    // ---- bitonic sort (128), descending, ties -> lower index
    for (int size = 2; size <= 128; size <<= 1) {
        for (int stride = size >> 1; stride > 0; stride >>= 1) {
            if (tid < 64) {
                int i = 2 * stride * (tid / stride) + (tid % stride);
                int j = i + stride;
                float si_ = sc[i], sj_ = sc[j];
                int ii = id[i], ij = id[j];
                bool iFirst = (si_ > sj_) || (si_ == sj_ && ii < ij);
                bool descRegion = ((i & size) == 0);
                bool doSwap = descRegion ? !iFirst : iFirst;
                if (doSwap) { sc[i] = sj_; sc[j] = si_; id[i] = ij; id[j] = ii; }
            }
            __syncthreads();
        }
    }

    // ---- gates + remap table
    for (int j = tid; j < KK; j += 1024) gate[j] = tanhf(sc[j]);
    if constexpr (!LAST) {
        for (int i = tid; i < NC; i += 1024) remap_l[i] = -1;
    }
    __syncthreads();
    if constexpr (!LAST) {
        for (int j = tid; j < KK; j += 1024) remap_l[id[j]] = j;
    }
    __syncthreads();

    // ---- fused edge remap (thread's own edge, regs)
    if constexpr (!LAST) {
        int s2 = remap_l[es_r], d2 = remap_l[ed_r];
        bool ok = (s2 >= 0) && (d2 >= 0);
        srcB[g * 1024 + tid] = ok ? s2 : 0;
        dstB[g * 1024 + tid] = ok ? d2 : 0;
        emB[g * 1024 + tid]  = ok ? em_r : 0.f;
    }

    // ---- gather + gate + x_new + partial readout (scratch aliases csr)
    float* pmax = (float*)&csr[0];       // [8][128]
    float* psum = pmax + 1024;           // [8][128]
    {
        const int f = tid & 127, jj = tid >> 7;
        float rmx = NINF, rsm = 0.f;
        for (int j = jj; j < KK; j += 8) {
            float v = h[((long)g * NC + id[j]) * 128 + f] * gate[j];
            if constexpr (!LAST) x_new[((long)g * KK + j) * 128 + f] = v;
            rmx = fmaxf(rmx, v);
            rsm += v;
        }
        pmax[jj * 128 + f] = rmx; psum[jj * 128 + f] = rsm;
    }
    __syncthreads();

    if (tid < 128) {
        float m = pmax[tid], s = psum[tid];
#pragma unroll
        for (int jj = 1; jj < 8; ++jj) { m = fmaxf(m, pmax[jj * 128 + tid]); s += psum[jj * 128 + tid]; }
        float mean = s / (float)KK;
        if constexpr (ACCUM) {
            z[g * 256 + tid] += m;
            z[g * 256 + 128 + tid] += mean;
        } else {
            z[g * 256 + tid] = m;
            z[g * 256 + 128 + tid] = mean;
        }
    }
}

// ---------------------------------------------------------------------------
// MLP tail per row: lin2 (1024->64) + lrelu + bn2, lin3 (64->2) + bias.
// ---------------------------------------------------------------------------
__global__ __launch_bounds__(256) void mlp_tail(
    const float* __restrict__ t1,
    const float* __restrict__ W2, const float* __restrict__ b2v,
    const float* __restrict__ g2, const float* __restrict__ bb2,
    const float* __restrict__ rm2, const float* __restrict__ rv2,
    const float* __restrict__ W3, const float* __restrict__ b3v,
    float* __restrict__ out)
{
    __shared__ float t1s[1024];
    __shared__ float part[4][64];
    __shared__ float t2s[64];
    const int row = blockIdx.x, tid = threadIdx.x;

    for (int i = tid; i < 1024; i += 256) t1s[i] = t1[(long)row * 1024 + i];
    __syncthreads();

    int c = tid & 63, seg = tid >> 6;
    float s = 0.f;
    for (int k = seg * 256; k < seg * 256 + 256; ++k)
        s = fmaf(t1s[k], W2[k * 64 + c], s);
    part[seg][c] = s;
    __syncthreads();

    if (tid < 64) {
        float v = part[0][c] + part[1][c] + part[2][c] + part[3][c] + b2v[c];
        v = v >= 0.f ? v : NEGS * v;
        v = (v - rm2[c]) * (1.0f / sqrtf(rv2[c] + BNEPS)) * g2[c] + bb2[c];
        t2s[c] = v;
    }
    __syncthreads();

    if (tid < 128) {
        int cc = tid >> 6, k = tid & 63;
        float prod = t2s[k] * W3[k * 2 + cc];
#pragma unroll
        for (int o = 32; o; o >>= 1) prod += __shfl_xor(prod, o, 64);
        if (k == 0) out[row * 2 + cc] = prod + b3v[cc];
    }
}

// ---------------------------------------------------------------------------
extern "C" void kernel_launch(void* const* d_in, const int* in_sizes, int n_in,
                              void* d_out, int out_size, void* d_ws, size_t ws_size,
                              hipStream_t stream)
{
    const float* x    = (const float*)d_in[0];
    const int*   src  = (const int*)d_in[1];
    const int*   dst  = (const int*)d_in[2];
    const float* W1   = (const float*)d_in[4];
    const float* b1   = (const float*)d_in[5];
    const float* W2   = (const float*)d_in[6];
    const float* b2   = (const float*)d_in[7];
    const float* W3   = (const float*)d_in[8];
    const float* b3   = (const float*)d_in[9];
    const float* p1   = (const float*)d_in[10];
    const float* p2   = (const float*)d_in[11];
    const float* p3   = (const float*)d_in[12];
    const float* l1W  = (const float*)d_in[13];
    const float* l1b  = (const float*)d_in[14];
    const float* l2W  = (const float*)d_in[15];
    const float* l2b  = (const float*)d_in[16];
    const float* l3W  = (const float*)d_in[17];
    const float* l3b  = (const float*)d_in[18];
    const float* bn1g = (const float*)d_in[19];
    const float* bn1b = (const float*)d_in[20];
    const float* bn1rm= (const float*)d_in[21];
    const float* bn1rv= (const float*)d_in[22];
    const float* bn2g = (const float*)d_in[23];
    const float* bn2b = (const float*)d_in[24];
    const float* bn2rm= (const float*)d_in[25];
    const float* bn2rv= (const float*)d_in[26];
    float* out = (float*)d_out;

    // workspace layout (floats)
    float* ws = (float*)d_ws;
    size_t o = 0;
    float* h_pre = ws + o; o += 65536L * 128;    // GEMM out / activated h (in-place)
    float* x_cur = ws + o; o += 52736L * 128;    // pooled x (reused every layer)
    float* z     = ws + o; o += 512L * 256;
    float* t1    = ws + o; o += 512L * 1024;
    int*   eSA   = (int*)(ws + o); o += 524288;
    int*   eDA   = (int*)(ws + o); o += 524288;
    float* emA   = ws + o; o += 524288;
    int*   eSB   = (int*)(ws + o); o += 524288;
    int*   eDB   = (int*)(ws + o); o += 524288;
    float* emB   = ws + o; o += 524288;

    // ---- Layer 1
    gemm_f32<64,128,16,4,8,0><<<dim3(1,1024), 256, 0, stream>>>(
        x, W1, h_pre, 65536, 128, 133, nullptr, nullptr, nullptr, nullptr, nullptr);
    gcn_topk<128,103,true,false,false><<<512, 1024, 0, stream>>>(
        h_pre, src, dst, nullptr, b1, p1, x_cur, eSA, eDA, emA, z);

    // ---- Layer 2
    gemm_f32<64,128,16,4,8,0><<<dim3(1,824), 256, 0, stream>>>(
        x_cur, W2, h_pre, 52736, 128, 128, nullptr, nullptr, nullptr, nullptr, nullptr);
    gcn_topk<103,83,false,false,true><<<512, 1024, 0, stream>>>(
        h_pre, eSA, eDA, emA, b2, p2, x_cur, eSB, eDB, emB, z);

    // ---- Layer 3
    gemm_f32<64,128,16,4,8,0><<<dim3(1,664), 256, 0, stream>>>(
        x_cur, W3, h_pre, 42496, 128, 128, nullptr, nullptr, nullptr, nullptr, nullptr);
    gcn_topk<83,67,false,true,true><<<512, 1024, 0, stream>>>(
        h_pre, eSB, eDB, emB, b3, p3, nullptr, nullptr, nullptr, nullptr, z);

    // ---- MLP head
    gemm_f32<16,128,16,1,8,1><<<dim3(8,32), 256, 0, stream>>>(
        z, l1W, t1, 512, 1024, 256, l1b, bn1g, bn1b, bn1rm, bn1rv);
    mlp_tail<<<512, 256, 0, stream>>>(
        t1, l2W, l2b, bn2g, bn2b, bn2rm, bn2rv, l3W, l3b, out);
}

// Round 5
// 306.472 us; speedup vs baseline: 5.4411x; 1.3765x over previous
//
#include <hip/hip_runtime.h>

#define NEGS 0.01f
#define BNEPS 1e-5f

typedef short bf16x8 __attribute__((ext_vector_type(8)));
typedef float f32x4 __attribute__((ext_vector_type(4)));

// split fp32 -> hi/lo bf16 (RNE), a ~= hi + lo with ~2^-18 rel residual
__device__ __forceinline__ void split2(float v, short& hi, short& lo) {
    unsigned u = __float_as_uint(v);
    unsigned r = (u + 0x7FFFu + ((u >> 16) & 1u)) >> 16;
    hi = (short)r;
    float hf = __uint_as_float(r << 16);
    float l = v - hf;
    unsigned ul = __float_as_uint(l);
    lo = (short)((ul + 0x7FFFu + ((ul >> 16) & 1u)) >> 16);
}

// ---------------------------------------------------------------------------
// Precompute: split all 4 weight matrices into hi/lo bf16, TRANSPOSED to
// [N][K32] rows (K zero-padded to K32), so the GEMM stages B with b128 loads.
// Segments: W1(133->160 x128) | W2(128x128) | W3 | lin1_W(256x1024).
// ---------------------------------------------------------------------------
__global__ __launch_bounds__(256) void split_all(
    const float* __restrict__ W1, const float* __restrict__ W2,
    const float* __restrict__ W3, const float* __restrict__ L1,
    short* __restrict__ h1, short* __restrict__ l1,
    short* __restrict__ h2, short* __restrict__ l2,
    short* __restrict__ h3, short* __restrict__ l3,
    short* __restrict__ h4, short* __restrict__ l4)
{
    int idx = blockIdx.x * 256 + threadIdx.x;
    const float* B; short *H, *L; int K, N, K32, loc;
    if (idx < 20480)      { B = W1; H = h1; L = l1; K = 133; N = 128;  K32 = 160; loc = idx; }
    else if (idx < 36864) { B = W2; H = h2; L = l2; K = 128; N = 128;  K32 = 128; loc = idx - 20480; }
    else if (idx < 53248) { B = W3; H = h3; L = l3; K = 128; N = 128;  K32 = 128; loc = idx - 36864; }
    else                  { B = L1; H = h4; L = l4; K = 256; N = 1024; K32 = 256; loc = idx - 53248; }
    int n = loc % N, k = loc / N;
    float v = (k < K) ? B[(long)k * N + n] : 0.f;
    short hi, lo; split2(v, hi, lo);
    H[(long)n * K32 + k] = hi;
    L[(long)n * K32 + k] = lo;
}

// ---------------------------------------------------------------------------
// bf16-split MFMA GEMM: C[M,N] = A[M,K] @ B[K,N] (B pre-split/transposed).
// BM=64, BN=128, 256 thr = 4 waves (2x2), K in 32-chunks. 3 MFMA per tile
// (hh + hl + lh). LDS rows padded to 40 bf16 (2-way-conflict-free b128).
// EPI 1: +bias, leaky-relu, batchnorm(eval) for the MLP head.
// ---------------------------------------------------------------------------
template<int KCH, int VEC, int EPI>
__global__ __launch_bounds__(256) void mfma_gemm(
    const float* __restrict__ A, const short* __restrict__ Bh_t,
    const short* __restrict__ Bl_t, float* __restrict__ C,
    int M, int N, int K,
    const float* __restrict__ bias, const float* __restrict__ bng,
    const float* __restrict__ bnb, const float* __restrict__ bnrm,
    const float* __restrict__ bnrv)
{
    constexpr int K32 = KCH * 32;
    __shared__ short Ahs[64 * 40], Als[64 * 40];
    __shared__ short Bhs[128 * 40], Bls[128 * 40];

    const int tid = threadIdx.x;
    const int bm = blockIdx.y * 64, bn = blockIdx.x * 128;
    const int lane = tid & 63, w = tid >> 6, wm = w >> 1, wn = w & 1;
    const int lm = lane & 15, lk = (lane >> 4) * 8;

    const int arow = tid >> 2, akl = (tid & 3) * 8;       // A stage: 4 thr/row
    const int brow = tid & 127, bhl = tid >> 7;           // B stage: hi|lo half
    const short* bsrc = bhl ? Bl_t : Bh_t;
    short* bdst = bhl ? Bls : Bhs;

    const f32x4 zz = {0.f, 0.f, 0.f, 0.f};
    f32x4 acc[2][4];
#pragma unroll
    for (int i = 0; i < 2; ++i)
#pragma unroll
        for (int j = 0; j < 4; ++j) acc[i][j] = zz;

    for (int c = 0; c < KCH; ++c) {
        // ---- stage A chunk (convert fp32 -> hi/lo bf16)
        float av[8];
        if constexpr (VEC == 4) {
            const float4 v0 = *(const float4*)&A[(long)(bm + arow) * K + c * 32 + akl];
            const float4 v1 = *(const float4*)&A[(long)(bm + arow) * K + c * 32 + akl + 4];
            av[0] = v0.x; av[1] = v0.y; av[2] = v0.z; av[3] = v0.w;
            av[4] = v1.x; av[5] = v1.y; av[6] = v1.z; av[7] = v1.w;
        } else {
#pragma unroll
            for (int j = 0; j < 8; ++j) {
                int k = c * 32 + akl + j;
                av[j] = (k < K) ? A[(long)(bm + arow) * K + k] : 0.f;
            }
        }
        bf16x8 h8, l8;
#pragma unroll
        for (int j = 0; j < 8; ++j) { short h_, l_; split2(av[j], h_, l_); h8[j] = h_; l8[j] = l_; }
        *(bf16x8*)&Ahs[arow * 40 + akl] = h8;
        *(bf16x8*)&Als[arow * 40 + akl] = l8;
        // ---- stage B chunk (pre-split bf16, row-major [n][k])
        const long bbase = (long)(bn + brow) * K32 + c * 32;
#pragma unroll
        for (int j = 0; j < 4; ++j)
            *(bf16x8*)&bdst[brow * 40 + j * 8] = *(const bf16x8*)&bsrc[bbase + j * 8];
        __syncthreads();

        // ---- MFMA: wave (wm,wn) owns rows wm*32..+32, cols wn*64..+64
        bf16x8 ah0 = *(const bf16x8*)&Ahs[(wm * 32 + lm) * 40 + lk];
        bf16x8 ah1 = *(const bf16x8*)&Ahs[(wm * 32 + 16 + lm) * 40 + lk];
        bf16x8 al0 = *(const bf16x8*)&Als[(wm * 32 + lm) * 40 + lk];
        bf16x8 al1 = *(const bf16x8*)&Als[(wm * 32 + 16 + lm) * 40 + lk];
#pragma unroll
        for (int nt = 0; nt < 4; ++nt) {
            bf16x8 bh = *(const bf16x8*)&Bhs[(wn * 64 + nt * 16 + lm) * 40 + lk];
            bf16x8 bl = *(const bf16x8*)&Bls[(wn * 64 + nt * 16 + lm) * 40 + lk];
            acc[0][nt] = __builtin_amdgcn_mfma_f32_16x16x32_bf16(ah0, bh, acc[0][nt], 0, 0, 0);
            acc[1][nt] = __builtin_amdgcn_mfma_f32_16x16x32_bf16(ah1, bh, acc[1][nt], 0, 0, 0);
            acc[0][nt] = __builtin_amdgcn_mfma_f32_16x16x32_bf16(ah0, bl, acc[0][nt], 0, 0, 0);
            acc[1][nt] = __builtin_amdgcn_mfma_f32_16x16x32_bf16(ah1, bl, acc[1][nt], 0, 0, 0);
            acc[0][nt] = __builtin_amdgcn_mfma_f32_16x16x32_bf16(al0, bh, acc[0][nt], 0, 0, 0);
            acc[1][nt] = __builtin_amdgcn_mfma_f32_16x16x32_bf16(al1, bh, acc[1][nt], 0, 0, 0);
        }
        __syncthreads();
    }

    // ---- epilogue: C/D map col=lane&15, row=(lane>>4)*4+reg (m89-verified)
#pragma unroll
    for (int mt = 0; mt < 2; ++mt) {
        int r0 = bm + wm * 32 + mt * 16 + (lane >> 4) * 4;
#pragma unroll
        for (int nt = 0; nt < 4; ++nt) {
            int col = bn + wn * 64 + nt * 16 + lm;
            float bi = 0.f, sc_ = 1.f, rm_ = 0.f, bb_ = 0.f;
            if (EPI == 1) {
                bi = bias[col];
                sc_ = (1.0f / sqrtf(bnrv[col] + BNEPS)) * bng[col];
                rm_ = bnrm[col]; bb_ = bnb[col];
            }
#pragma unroll
            for (int r = 0; r < 4; ++r) {
                float v = acc[mt][nt][r];
                if (EPI == 1) {
                    v += bi;
                    v = v >= 0.f ? v : NEGS * v;
                    v = (v - rm_) * sc_ + bb_;
                }
                C[(long)(r0 + r) * N + col] = v;
            }
        }
    }
}

// ---------------------------------------------------------------------------
// Fused per-graph: GCN finish (CSR build + atomic-free gather-aggregate +
// self-loop + bias + lrelu, in-place to global h) + TopK + IN-PLACE edge
// remap + gather/x_new + readout. 1024 thr, ~77KB LDS -> 2 blocks/CU.
// ---------------------------------------------------------------------------
template<int NC, int KK, bool FIRST, bool LAST, bool ACCUM>
__global__ __launch_bounds__(1024, 8) void gcn_topk(
    float* __restrict__ h,               // [G*NC,128] in: x@W ; out: activated
    const int* __restrict__ srcIn, const int* __restrict__ dstIn, // FIRST only
    int* eS, int* eD, float* eM,         // edge buffers, remapped IN PLACE
    const float* __restrict__ bias, const float* __restrict__ p,
    float* __restrict__ x_new,           // [G*KK,128]   (null when LAST)
    float* __restrict__ z)               // [G,256]
{
    __shared__ float h_s[NC][128];
    __shared__ float2 csr[1024];         // (src_as_float, coef); later readout scratch
    __shared__ int   head[NC];
    __shared__ float deg_s[NC], dis_s[NC], invd_s[NC];
    __shared__ float sc[128];
    __shared__ int   id[128];
    __shared__ float gate[KK];
    __shared__ float b_s[128], p_s[128];
    __shared__ int   remap_l[NC];
    __shared__ float pnorm;

    const int g = blockIdx.x, tid = threadIdx.x, lane = tid & 63;
    const float NINF = -__builtin_inff();

    // ---- edge in registers (one per thread; slot g*1024+tid owned by thread)
    int es_r, ed_r; float em_r;
    {
        int eg = g * 1024 + tid;
        if (FIRST) { es_r = srcIn[eg] & 127; ed_r = dstIn[eg] & 127; em_r = 1.f; }
        else       { es_r = eS[eg];          ed_r = eD[eg];          em_r = eM[eg]; }
    }

    // ---- stage h tile (float4) + init
    {
        const float4* hp = (const float4*)(h + (long)g * NC * 128);
        float4* h4 = (float4*)&h_s[0][0];
        for (int i = tid; i < NC * 32; i += 1024) h4[i] = hp[i];
    }
    if (tid < 128) { b_s[tid] = bias[tid]; p_s[tid] = p[tid]; sc[tid] = 0.f; }
    for (int i = tid; i < NC; i += 1024) { deg_s[i] = 1.f; head[i] = 0; }
    __syncthreads();

    // ---- ||p|| (wave0) + degree/count histograms (masked edges excluded)
    if (tid < 64) {
        float s = p_s[tid] * p_s[tid] + p_s[tid + 64] * p_s[tid + 64];
#pragma unroll
        for (int o = 32; o; o >>= 1) s += __shfl_xor(s, o, 64);
        if (tid == 0) pnorm = sqrtf(s);
    }
    const bool live = FIRST || (em_r != 0.f);
    if (live) {
        atomicAdd(&deg_s[ed_r], em_r);
        atomicAdd(&head[ed_r], 1);
    }
    __syncthreads();

    for (int i = tid; i < NC; i += 1024) {
        float d = deg_s[i];
        dis_s[i] = 1.0f / sqrtf(d);
        invd_s[i] = 1.0f / d;
    }
    // ---- exclusive scan of counts -> head (wave0, shfl)
    if (tid < 64) {
        int c0 = head[tid];
        int c1 = (tid + 64 < NC) ? head[tid + 64] : 0;
        int s0 = c0, s1 = c1;
#pragma unroll
        for (int o = 1; o < 64; o <<= 1) { int t = __shfl_up(s0, o, 64); if (lane >= o) s0 += t; }
        int tot0 = __shfl(s0, 63, 64);
#pragma unroll
        for (int o = 1; o < 64; o <<= 1) { int t = __shfl_up(s1, o, 64); if (lane >= o) s1 += t; }
        s1 += tot0;
        head[tid] = s0 - c0;
        if (tid + 64 < NC) head[tid + 64] = s1 - c1;
    }
    __syncthreads();

    // ---- CSR place (head becomes per-node END offset afterwards)
    if (live) {
        int slot = atomicAdd(&head[ed_r], 1);
        csr[slot] = make_float2(__int_as_float(es_r), dis_s[es_r] * dis_s[ed_r] * em_r);
    }
    __syncthreads();

    // ---- atomic-free gather aggregate + act + in-place write-back + score
    {
        const int f = tid & 127, grp = tid >> 7;
        for (int nd = grp; nd < NC; nd += 8) {
            int kb = nd ? head[nd - 1] : 0;
            int ke = head[nd];
            float acc = 0.f;
            for (int k = kb; k < ke; ++k) {
                float2 rec = csr[k];
                acc += h_s[__float_as_int(rec.x)][f] * rec.y;
            }
            float v = acc + h_s[nd][f] * invd_s[nd] + b_s[f];
            v = v >= 0.f ? v : NEGS * v;
            h[((long)g * NC + nd) * 128 + f] = v;     // in-place act (global)
            float ps = v * p_s[f];
#pragma unroll
            for (int o = 32; o; o >>= 1) ps += __shfl_xor(ps, o, 64);
            if (lane == 0) atomicAdd(&sc[nd], ps);
        }
    }
    __syncthreads();

    // ---- finalize scores
    if (tid < 128) {
        if (tid < NC) { sc[tid] = sc[tid] / pnorm; id[tid] = tid; }
        else          { sc[tid] = NINF; id[tid] = 0x7fffffff; }
    }
    __syncthreads();

    // ---- bitonic sort (128), descending, ties -> lower index
    for (int size = 2; size <= 128; size <<= 1) {
        for (int stride = size >> 1; stride > 0; stride >>= 1) {
            if (tid < 64) {
                int i = 2 * stride * (tid / stride) + (tid % stride);
                int j = i + stride;
                float si_ = sc[i], sj_ = sc[j];
                int ii = id[i], ij = id[j];
                bool iFirst = (si_ > sj_) || (si_ == sj_ && ii < ij);
                bool descRegion = ((i & size) == 0);
                bool doSwap = descRegion ? !iFirst : iFirst;
                if (doSwap) { sc[i] = sj_; sc[j] = si_; id[i] = ij; id[j] = ii; }
            }
            __syncthreads();
        }
    }

    // ---- gates + remap table
    for (int j = tid; j < KK; j += 1024) gate[j] = tanhf(sc[j]);
    if constexpr (!LAST) {
        for (int i = tid; i < NC; i += 1024) remap_l[i] = -1;
    }
    __syncthreads();
    if constexpr (!LAST) {
        for (int j = tid; j < KK; j += 1024) remap_l[id[j]] = j;
    }
    __syncthreads();

    // ---- fused IN-PLACE edge remap (thread's own slot, read long ago)
    if constexpr (!LAST) {
        int s2 = remap_l[es_r], d2 = remap_l[ed_r];
        bool ok = (s2 >= 0) && (d2 >= 0);
        eS[g * 1024 + tid] = ok ? s2 : 0;
        eD[g * 1024 + tid] = ok ? d2 : 0;
        eM[g * 1024 + tid] = ok ? em_r : 0.f;
    }

    // ---- gather + gate + x_new + partial readout (scratch aliases csr)
    float* pmax = (float*)&csr[0];       // [8][128]
    float* psum = pmax + 1024;           // [8][128]
    {
        const int f = tid & 127, jj = tid >> 7;
        float rmx = NINF, rsm = 0.f;
        for (int j = jj; j < KK; j += 8) {
            float v = h[((long)g * NC + id[j]) * 128 + f] * gate[j];
            if constexpr (!LAST) x_new[((long)g * KK + j) * 128 + f] = v;
            rmx = fmaxf(rmx, v);
            rsm += v;
        }
        pmax[jj * 128 + f] = rmx; psum[jj * 128 + f] = rsm;
    }
    __syncthreads();

    if (tid < 128) {
        float m = pmax[tid], s = psum[tid];
#pragma unroll
        for (int jj = 1; jj < 8; ++jj) { m = fmaxf(m, pmax[jj * 128 + tid]); s += psum[jj * 128 + tid]; }
        float mean = s / (float)KK;
        if constexpr (ACCUM) {
            z[g * 256 + tid] += m;
            z[g * 256 + 128 + tid] += mean;
        } else {
            z[g * 256 + tid] = m;
            z[g * 256 + 128 + tid] = mean;
        }
    }
}

// ---------------------------------------------------------------------------
// MLP tail per row: lin2 (1024->64) + lrelu + bn2, lin3 (64->2) + bias.
// ---------------------------------------------------------------------------
__global__ __launch_bounds__(256) void mlp_tail(
    const float* __restrict__ t1,
    const float* __restrict__ W2, const float* __restrict__ b2v,
    const float* __restrict__ g2, const float* __restrict__ bb2,
    const float* __restrict__ rm2, const float* __restrict__ rv2,
    const float* __restrict__ W3, const float* __restrict__ b3v,
    float* __restrict__ out)
{
    __shared__ float t1s[1024];
    __shared__ float part[4][64];
    __shared__ float t2s[64];
    const int row = blockIdx.x, tid = threadIdx.x;

    for (int i = tid; i < 1024; i += 256) t1s[i] = t1[(long)row * 1024 + i];
    __syncthreads();

    int c = tid & 63, seg = tid >> 6;
    float s = 0.f;
    for (int k = seg * 256; k < seg * 256 + 256; ++k)
        s = fmaf(t1s[k], W2[k * 64 + c], s);
    part[seg][c] = s;
    __syncthreads();

    if (tid < 64) {
        float v = part[0][c] + part[1][c] + part[2][c] + part[3][c] + b2v[c];
        v = v >= 0.f ? v : NEGS * v;
        v = (v - rm2[c]) * (1.0f / sqrtf(rv2[c] + BNEPS)) * g2[c] + bb2[c];
        t2s[c] = v;
    }
    __syncthreads();

    if (tid < 128) {
        int cc = tid >> 6, k = tid & 63;
        float prod = t2s[k] * W3[k * 2 + cc];
#pragma unroll
        for (int o = 32; o; o >>= 1) prod += __shfl_xor(prod, o, 64);
        if (k == 0) out[row * 2 + cc] = prod + b3v[cc];
    }
}

// ---------------------------------------------------------------------------
extern "C" void kernel_launch(void* const* d_in, const int* in_sizes, int n_in,
                              void* d_out, int out_size, void* d_ws, size_t ws_size,
                              hipStream_t stream)
{
    const float* x    = (const float*)d_in[0];
    const int*   src  = (const int*)d_in[1];
    const int*   dst  = (const int*)d_in[2];
    const float* W1   = (const float*)d_in[4];
    const float* b1   = (const float*)d_in[5];
    const float* W2   = (const float*)d_in[6];
    const float* b2   = (const float*)d_in[7];
    const float* W3   = (const float*)d_in[8];
    const float* b3   = (const float*)d_in[9];
    const float* p1   = (const float*)d_in[10];
    const float* p2   = (const float*)d_in[11];
    const float* p3   = (const float*)d_in[12];
    const float* l1W  = (const float*)d_in[13];
    const float* l1b  = (const float*)d_in[14];
    const float* l2W  = (const float*)d_in[15];
    const float* l2b  = (const float*)d_in[16];
    const float* l3W  = (const float*)d_in[17];
    const float* l3b  = (const float*)d_in[18];
    const float* bn1g = (const float*)d_in[19];
    const float* bn1b = (const float*)d_in[20];
    const float* bn1rm= (const float*)d_in[21];
    const float* bn1rv= (const float*)d_in[22];
    const float* bn2g = (const float*)d_in[23];
    const float* bn2b = (const float*)d_in[24];
    const float* bn2rm= (const float*)d_in[25];
    const float* bn2rv= (const float*)d_in[26];
    float* out = (float*)d_out;

    // workspace layout (floats)
    float* ws = (float*)d_ws;
    size_t o = 0;
    float* h_pre = ws + o; o += 65536L * 128;    // GEMM out / activated h (in-place)
    float* x_cur = ws + o; o += 52736L * 128;    // pooled x (reused every layer)
    float* z     = ws + o; o += 512L * 256;
    float* t1    = ws + o; o += 512L * 1024;
    int*   eSA   = (int*)(ws + o); o += 524288;
    int*   eDA   = (int*)(ws + o); o += 524288;
    float* emA   = ws + o; o += 524288;
    // bf16-split weights (shorts), carved from the float arena
    short* sp = (short*)(ws + o);
    short* h1s = sp;               // W1 hi  [128][160]
    short* l1s = h1s + 20480;      // W1 lo
    short* h2s = l1s + 20480;      // W2 hi  [128][128]
    short* l2s = h2s + 16384;
    short* h3s = l2s + 16384;      // W3 hi
    short* l3s = h3s + 16384;
    short* h4s = l3s + 16384;      // lin1_W hi [1024][256]
    short* l4s = h4s + 262144;     // lin1_W lo (+262144 end)

    // ---- precompute weight splits (tiny)
    split_all<<<1232, 256, 0, stream>>>(W1, W2, W3, l1W,
        h1s, l1s, h2s, l2s, h3s, l3s, h4s, l4s);

    // ---- Layer 1: h = x @ W1  (M=65536, K=133->160)
    mfma_gemm<5,1,0><<<dim3(1,1024), 256, 0, stream>>>(
        x, h1s, l1s, h_pre, 65536, 128, 133, nullptr, nullptr, nullptr, nullptr, nullptr);
    gcn_topk<128,103,true,false,false><<<512, 1024, 0, stream>>>(
        h_pre, src, dst, eSA, eDA, emA, b1, p1, x_cur, z);

    // ---- Layer 2: h = x2 @ W2  (M=52736, K=128)
    mfma_gemm<4,4,0><<<dim3(1,824), 256, 0, stream>>>(
        x_cur, h2s, l2s, h_pre, 52736, 128, 128, nullptr, nullptr, nullptr, nullptr, nullptr);
    gcn_topk<103,83,false,false,true><<<512, 1024, 0, stream>>>(
        h_pre, nullptr, nullptr, eSA, eDA, emA, b2, p2, x_cur, z);

    // ---- Layer 3: h = x3 @ W3  (M=42496, K=128)
    mfma_gemm<4,4,0><<<dim3(1,664), 256, 0, stream>>>(
        x_cur, h3s, l3s, h_pre, 42496, 128, 128, nullptr, nullptr, nullptr, nullptr, nullptr);
    gcn_topk<83,67,false,true,true><<<512, 1024, 0, stream>>>(
        h_pre, nullptr, nullptr, eSA, eDA, emA, b3, p3, nullptr, z);

    // ---- MLP head: t1 = bn1(lrelu(z @ lin1_W + b))  (M=512, N=1024, K=256)
    mfma_gemm<8,4,1><<<dim3(8,8), 256, 0, stream>>>(
        z, h4s, l4s, t1, 512, 1024, 256, l1b, bn1g, bn1b, bn1rm, bn1rv);
    mlp_tail<<<512, 256, 0, stream>>>(
        t1, l2W, l2b, bn2g, bn2b, bn2rm, bn2rv, l3W, l3b, out);
}

// Round 6
// 296.494 us; speedup vs baseline: 5.6242x; 1.0337x over previous
//
#include <hip/hip_runtime.h>

#define NEGS 0.01f
#define BNEPS 1e-5f

typedef short bf16x8 __attribute__((ext_vector_type(8)));
typedef float f32x4 __attribute__((ext_vector_type(4)));

// split fp32 -> hi/lo bf16 (RNE), a ~= hi + lo with ~2^-18 rel residual
__device__ __forceinline__ void split2(float v, short& hi, short& lo) {
    unsigned u = __float_as_uint(v);
    unsigned r = (u + 0x7FFFu + ((u >> 16) & 1u)) >> 16;
    hi = (short)r;
    float hf = __uint_as_float(r << 16);
    float l = v - hf;
    unsigned ul = __float_as_uint(l);
    lo = (short)((ul + 0x7FFFu + ((ul >> 16) & 1u)) >> 16);
}

// ---------------------------------------------------------------------------
// Precompute: split all 4 weight matrices into hi/lo bf16, TRANSPOSED to
// [N][K32] rows (K zero-padded), so the GEMM stages B with b128 loads.
// ---------------------------------------------------------------------------
__global__ __launch_bounds__(256) void split_all(
    const float* __restrict__ W1, const float* __restrict__ W2,
    const float* __restrict__ W3, const float* __restrict__ L1,
    short* __restrict__ h1, short* __restrict__ l1,
    short* __restrict__ h2, short* __restrict__ l2,
    short* __restrict__ h3, short* __restrict__ l3,
    short* __restrict__ h4, short* __restrict__ l4)
{
    int idx = blockIdx.x * 256 + threadIdx.x;
    const float* B; short *H, *L; int K, N, K32, loc;
    if (idx < 20480)      { B = W1; H = h1; L = l1; K = 133; N = 128;  K32 = 160; loc = idx; }
    else if (idx < 36864) { B = W2; H = h2; L = l2; K = 128; N = 128;  K32 = 128; loc = idx - 20480; }
    else if (idx < 53248) { B = W3; H = h3; L = l3; K = 128; N = 128;  K32 = 128; loc = idx - 36864; }
    else                  { B = L1; H = h4; L = l4; K = 256; N = 1024; K32 = 256; loc = idx - 53248; }
    int n = loc % N, k = loc / N;
    float v = (k < K) ? B[(long)k * N + n] : 0.f;
    short hi, lo; split2(v, hi, lo);
    H[(long)n * K32 + k] = hi;
    L[(long)n * K32 + k] = lo;
}

// ---------------------------------------------------------------------------
// bf16-split MFMA GEMM: C[M,N] = A[M,K] @ B[K,N] (B pre-split/transposed).
// BM=64, BN=128, 4 waves (2x2), K in 32-chunks, 3-term split (hh+hl+lh).
// EPI 1: +bias, leaky-relu, batchnorm(eval) for the MLP head.
// ---------------------------------------------------------------------------
template<int KCH, int VEC, int EPI>
__global__ __launch_bounds__(256) void mfma_gemm(
    const float* __restrict__ A, const short* __restrict__ Bh_t,
    const short* __restrict__ Bl_t, float* __restrict__ C,
    int M, int N, int K,
    const float* __restrict__ bias, const float* __restrict__ bng,
    const float* __restrict__ bnb, const float* __restrict__ bnrm,
    const float* __restrict__ bnrv)
{
    constexpr int K32 = KCH * 32;
    __shared__ short Ahs[64 * 40], Als[64 * 40];
    __shared__ short Bhs[128 * 40], Bls[128 * 40];

    const int tid = threadIdx.x;
    const int bm = blockIdx.y * 64, bn = blockIdx.x * 128;
    const int lane = tid & 63, w = tid >> 6, wm = w >> 1, wn = w & 1;
    const int lm = lane & 15, lk = (lane >> 4) * 8;

    const int arow = tid >> 2, akl = (tid & 3) * 8;
    const int brow = tid & 127, bhl = tid >> 7;
    const short* bsrc = bhl ? Bl_t : Bh_t;
    short* bdst = bhl ? Bls : Bhs;

    const f32x4 zz = {0.f, 0.f, 0.f, 0.f};
    f32x4 acc[2][4];
#pragma unroll
    for (int i = 0; i < 2; ++i)
#pragma unroll
        for (int j = 0; j < 4; ++j) acc[i][j] = zz;

    for (int c = 0; c < KCH; ++c) {
        float av[8];
        if constexpr (VEC == 4) {
            const float4 v0 = *(const float4*)&A[(long)(bm + arow) * K + c * 32 + akl];
            const float4 v1 = *(const float4*)&A[(long)(bm + arow) * K + c * 32 + akl + 4];
            av[0] = v0.x; av[1] = v0.y; av[2] = v0.z; av[3] = v0.w;
            av[4] = v1.x; av[5] = v1.y; av[6] = v1.z; av[7] = v1.w;
        } else {
#pragma unroll
            for (int j = 0; j < 8; ++j) {
                int k = c * 32 + akl + j;
                av[j] = (k < K) ? A[(long)(bm + arow) * K + k] : 0.f;
            }
        }
        bf16x8 h8, l8;
#pragma unroll
        for (int j = 0; j < 8; ++j) { short h_, l_; split2(av[j], h_, l_); h8[j] = h_; l8[j] = l_; }
        *(bf16x8*)&Ahs[arow * 40 + akl] = h8;
        *(bf16x8*)&Als[arow * 40 + akl] = l8;
        const long bbase = (long)(bn + brow) * K32 + c * 32;
#pragma unroll
        for (int j = 0; j < 4; ++j)
            *(bf16x8*)&bdst[brow * 40 + j * 8] = *(const bf16x8*)&bsrc[bbase + j * 8];
        __syncthreads();

        bf16x8 ah0 = *(const bf16x8*)&Ahs[(wm * 32 + lm) * 40 + lk];
        bf16x8 ah1 = *(const bf16x8*)&Ahs[(wm * 32 + 16 + lm) * 40 + lk];
        bf16x8 al0 = *(const bf16x8*)&Als[(wm * 32 + lm) * 40 + lk];
        bf16x8 al1 = *(const bf16x8*)&Als[(wm * 32 + 16 + lm) * 40 + lk];
#pragma unroll
        for (int nt = 0; nt < 4; ++nt) {
            bf16x8 bh = *(const bf16x8*)&Bhs[(wn * 64 + nt * 16 + lm) * 40 + lk];
            bf16x8 bl = *(const bf16x8*)&Bls[(wn * 64 + nt * 16 + lm) * 40 + lk];
            acc[0][nt] = __builtin_amdgcn_mfma_f32_16x16x32_bf16(ah0, bh, acc[0][nt], 0, 0, 0);
            acc[1][nt] = __builtin_amdgcn_mfma_f32_16x16x32_bf16(ah1, bh, acc[1][nt], 0, 0, 0);
            acc[0][nt] = __builtin_amdgcn_mfma_f32_16x16x32_bf16(ah0, bl, acc[0][nt], 0, 0, 0);
            acc[1][nt] = __builtin_amdgcn_mfma_f32_16x16x32_bf16(ah1, bl, acc[1][nt], 0, 0, 0);
            acc[0][nt] = __builtin_amdgcn_mfma_f32_16x16x32_bf16(al0, bh, acc[0][nt], 0, 0, 0);
            acc[1][nt] = __builtin_amdgcn_mfma_f32_16x16x32_bf16(al1, bh, acc[1][nt], 0, 0, 0);
        }
        __syncthreads();
    }

#pragma unroll
    for (int mt = 0; mt < 2; ++mt) {
        int r0 = bm + wm * 32 + mt * 16 + (lane >> 4) * 4;
#pragma unroll
        for (int nt = 0; nt < 4; ++nt) {
            int col = bn + wn * 64 + nt * 16 + lm;
            float bi = 0.f, sc_ = 1.f, rm_ = 0.f, bb_ = 0.f;
            if (EPI == 1) {
                bi = bias[col];
                sc_ = (1.0f / sqrtf(bnrv[col] + BNEPS)) * bng[col];
                rm_ = bnrm[col]; bb_ = bnb[col];
            }
#pragma unroll
            for (int r = 0; r < 4; ++r) {
                float v = acc[mt][nt][r];
                if (EPI == 1) {
                    v += bi;
                    v = v >= 0.f ? v : NEGS * v;
                    v = (v - rm_) * sc_ + bb_;
                }
                C[(long)(r0 + r) * N + col] = v;
            }
        }
    }
}

// ---------------------------------------------------------------------------
// Fused per-graph: GCN finish (CSR, atomic-free gather-agg, act kept in LDS)
// + TopK (wave0 bitonic sort) + in-place packed-edge remap + gather/x_new
// + readout. Edges packed: s | d<<7 | live<<14 (em is provably 0/1).
// 1024 thr, ~77KB LDS -> 2 blocks/CU.
// ---------------------------------------------------------------------------
template<int NC, int KK, bool FIRST, bool LAST, bool ACCUM>
__global__ __launch_bounds__(1024, 8) void gcn_topk(
    const float* __restrict__ h_pre,     // [G*NC,128] = x @ W (read-only)
    const int* __restrict__ srcIn, const int* __restrict__ dstIn, // FIRST only
    int* ePK,                            // packed edges, remapped IN PLACE
    const float* __restrict__ bias, const float* __restrict__ p,
    float* __restrict__ x_new,           // [G*KK,128]   (null when LAST)
    float* __restrict__ z)               // [G,256]
{
    __shared__ float h_s[NC][128];
    __shared__ float2 csr[1024];         // (src_as_float, coef); later readout scratch
    __shared__ int   head[NC];
    __shared__ float deg_s[NC], dis_s[NC], invd_s[NC];
    __shared__ float sc[128];
    __shared__ int   id[128];
    __shared__ float gate[KK];
    __shared__ float b_s[128], p_s[128];
    __shared__ int   remap_l[NC];
    __shared__ float pnorm;

    const int g = blockIdx.x, tid = threadIdx.x, lane = tid & 63;
    const float NINF = -__builtin_inff();
    constexpr int NITER = (NC + 7) / 8;

    // ---- edge in registers (one per thread; slot g*1024+tid owned by thread)
    int es_r, ed_r; bool live;
    {
        int eg = g * 1024 + tid;
        if (FIRST) { es_r = srcIn[eg] & 127; ed_r = dstIn[eg] & 127; live = true; }
        else       { int pk = ePK[eg]; es_r = pk & 127; ed_r = (pk >> 7) & 127; live = (pk >> 14) != 0; }
    }

    // ---- stage h tile (float4) + init
    {
        const float4* hp = (const float4*)(h_pre + (long)g * NC * 128);
        float4* h4 = (float4*)&h_s[0][0];
        for (int i = tid; i < NC * 32; i += 1024) h4[i] = hp[i];
    }
    if (tid < 128) { b_s[tid] = bias[tid]; p_s[tid] = p[tid]; sc[tid] = 0.f; }
    for (int i = tid; i < NC; i += 1024) { deg_s[i] = 1.f; head[i] = 0; }
    __syncthreads();

    // ---- ||p|| (wave0) + degree/count histograms (dead edges excluded)
    if (tid < 64) {
        float s = p_s[tid] * p_s[tid] + p_s[tid + 64] * p_s[tid + 64];
#pragma unroll
        for (int o = 32; o; o >>= 1) s += __shfl_xor(s, o, 64);
        if (tid == 0) pnorm = sqrtf(s);
    }
    if (live) {
        atomicAdd(&deg_s[ed_r], 1.0f);
        atomicAdd(&head[ed_r], 1);
    }
    __syncthreads();

    for (int i = tid; i < NC; i += 1024) {
        float d = deg_s[i];
        dis_s[i] = 1.0f / sqrtf(d);
        invd_s[i] = 1.0f / d;
    }
    // ---- exclusive scan of counts -> head (wave0, shfl)
    if (tid < 64) {
        int c0 = head[tid];
        int c1 = (tid + 64 < NC) ? head[tid + 64] : 0;
        int s0 = c0, s1 = c1;
#pragma unroll
        for (int o = 1; o < 64; o <<= 1) { int t = __shfl_up(s0, o, 64); if (lane >= o) s0 += t; }
        int tot0 = __shfl(s0, 63, 64);
#pragma unroll
        for (int o = 1; o < 64; o <<= 1) { int t = __shfl_up(s1, o, 64); if (lane >= o) s1 += t; }
        s1 += tot0;
        head[tid] = s0 - c0;
        if (tid + 64 < NC) head[tid + 64] = s1 - c1;
    }
    __syncthreads();

    // ---- CSR place (head becomes per-node END offset afterwards)
    if (live) {
        int slot = atomicAdd(&head[ed_r], 1);
        csr[slot] = make_float2(__int_as_float(es_r), dis_s[es_r] * dis_s[ed_r]);
    }
    __syncthreads();

    // ---- atomic-free gather aggregate + act (registers, static idx) + score
    float va[NITER];
    {
        const int f = tid & 127, grp = tid >> 7;
#pragma unroll
        for (int i = 0; i < NITER; ++i) {
            int nd = grp + i * 8;
            if (nd < NC) {
                int kb = nd ? head[nd - 1] : 0;
                int ke = head[nd];
                float acc = 0.f;
                for (int k = kb; k < ke; ++k) {
                    float2 rec = csr[k];
                    acc += h_s[__float_as_int(rec.x)][f] * rec.y;
                }
                float v = acc + h_s[nd][f] * invd_s[nd] + b_s[f];
                v = v >= 0.f ? v : NEGS * v;
                va[i] = v;
                float ps = v * p_s[f];
#pragma unroll
                for (int o = 32; o; o >>= 1) ps += __shfl_xor(ps, o, 64);
                if (lane == 0) atomicAdd(&sc[nd], ps);
            }
        }
    }
    __syncthreads();   // all h_s reads done -> safe to overwrite

    // ---- overwrite h_s with activated values (LDS-resident, no global trip)
    {
        const int f = tid & 127, grp = tid >> 7;
#pragma unroll
        for (int i = 0; i < NITER; ++i) {
            int nd = grp + i * 8;
            if (nd < NC) h_s[nd][f] = va[i];
        }
    }
    __syncthreads();

    // ---- finalize scores
    if (tid < 128) {
        if (tid < NC) { sc[tid] = sc[tid] / pnorm; id[tid] = tid; }
        else          { sc[tid] = NINF; id[tid] = 0x7fffffff; }
    }
    __syncthreads();

    // ---- bitonic sort (128) on wave 0 only: lockstep lanes, no block barriers
    if (tid < 64) {
        for (int size = 2; size <= 128; size <<= 1) {
            for (int stride = size >> 1; stride > 0; stride >>= 1) {
                int i = 2 * stride * (tid / stride) + (tid % stride);
                int j = i + stride;
                float si_ = sc[i], sj_ = sc[j];
                int ii = id[i], ij = id[j];
                bool iFirst = (si_ > sj_) || (si_ == sj_ && ii < ij);
                bool descRegion = ((i & size) == 0);
                bool doSwap = descRegion ? !iFirst : iFirst;
                if (doSwap) { sc[i] = sj_; sc[j] = si_; id[i] = ij; id[j] = ii; }
                __asm__ volatile("" ::: "memory");   // stage ordering / no LDS reg-caching
            }
        }
    }
    __syncthreads();

    // ---- gates + remap table
    for (int j = tid; j < KK; j += 1024) gate[j] = tanhf(sc[j]);
    if constexpr (!LAST) {
        for (int i = tid; i < NC; i += 1024) remap_l[i] = -1;
    }
    __syncthreads();
    if constexpr (!LAST) {
        for (int j = tid; j < KK; j += 1024) remap_l[id[j]] = j;
    }
    __syncthreads();

    // ---- fused IN-PLACE packed edge remap (thread's own slot)
    if constexpr (!LAST) {
        int s2 = remap_l[es_r], d2 = remap_l[ed_r];
        bool ok = (s2 >= 0) && (d2 >= 0);
        int lv = (live && ok) ? 1 : 0;
        ePK[g * 1024 + tid] = (ok ? s2 : 0) | ((ok ? d2 : 0) << 7) | (lv << 14);
    }

    // ---- gather (LDS) + gate + x_new + partial readout (scratch aliases csr)
    float* pmax = (float*)&csr[0];       // [8][128]
    float* psum = pmax + 1024;           // [8][128]
    {
        const int f = tid & 127, jj = tid >> 7;
        float rmx = NINF, rsm = 0.f;
        for (int j = jj; j < KK; j += 8) {
            float v = h_s[id[j]][f] * gate[j];
            if constexpr (!LAST) x_new[((long)g * KK + j) * 128 + f] = v;
            rmx = fmaxf(rmx, v);
            rsm += v;
        }
        pmax[jj * 128 + f] = rmx; psum[jj * 128 + f] = rsm;
    }
    __syncthreads();

    if (tid < 128) {
        float m = pmax[tid], s = psum[tid];
#pragma unroll
        for (int jj = 1; jj < 8; ++jj) { m = fmaxf(m, pmax[jj * 128 + tid]); s += psum[jj * 128 + tid]; }
        float mean = s / (float)KK;
        if constexpr (ACCUM) {
            z[g * 256 + tid] += m;
            z[g * 256 + 128 + tid] += mean;
        } else {
            z[g * 256 + tid] = m;
            z[g * 256 + 128 + tid] = mean;
        }
    }
}

// ---------------------------------------------------------------------------
// MLP tail per row: lin2 (1024->64) + lrelu + bn2, lin3 (64->2) + bias.
// ---------------------------------------------------------------------------
__global__ __launch_bounds__(256) void mlp_tail(
    const float* __restrict__ t1,
    const float* __restrict__ W2, const float* __restrict__ b2v,
    const float* __restrict__ g2, const float* __restrict__ bb2,
    const float* __restrict__ rm2, const float* __restrict__ rv2,
    const float* __restrict__ W3, const float* __restrict__ b3v,
    float* __restrict__ out)
{
    __shared__ float t1s[1024];
    __shared__ float part[4][64];
    __shared__ float t2s[64];
    const int row = blockIdx.x, tid = threadIdx.x;

    for (int i = tid; i < 1024; i += 256) t1s[i] = t1[(long)row * 1024 + i];
    __syncthreads();

    int c = tid & 63, seg = tid >> 6;
    float s = 0.f;
    for (int k = seg * 256; k < seg * 256 + 256; ++k)
        s = fmaf(t1s[k], W2[k * 64 + c], s);
    part[seg][c] = s;
    __syncthreads();

    if (tid < 64) {
        float v = part[0][c] + part[1][c] + part[2][c] + part[3][c] + b2v[c];
        v = v >= 0.f ? v : NEGS * v;
        v = (v - rm2[c]) * (1.0f / sqrtf(rv2[c] + BNEPS)) * g2[c] + bb2[c];
        t2s[c] = v;
    }
    __syncthreads();

    if (tid < 128) {
        int cc = tid >> 6, k = tid & 63;
        float prod = t2s[k] * W3[k * 2 + cc];
#pragma unroll
        for (int o = 32; o; o >>= 1) prod += __shfl_xor(prod, o, 64);
        if (k == 0) out[row * 2 + cc] = prod + b3v[cc];
    }
}

// ---------------------------------------------------------------------------
extern "C" void kernel_launch(void* const* d_in, const int* in_sizes, int n_in,
                              void* d_out, int out_size, void* d_ws, size_t ws_size,
                              hipStream_t stream)
{
    const float* x    = (const float*)d_in[0];
    const int*   src  = (const int*)d_in[1];
    const int*   dst  = (const int*)d_in[2];
    const float* W1   = (const float*)d_in[4];
    const float* b1   = (const float*)d_in[5];
    const float* W2   = (const float*)d_in[6];
    const float* b2   = (const float*)d_in[7];
    const float* W3   = (const float*)d_in[8];
    const float* b3   = (const float*)d_in[9];
    const float* p1   = (const float*)d_in[10];
    const float* p2   = (const float*)d_in[11];
    const float* p3   = (const float*)d_in[12];
    const float* l1W  = (const float*)d_in[13];
    const float* l1b  = (const float*)d_in[14];
    const float* l2W  = (const float*)d_in[15];
    const float* l2b  = (const float*)d_in[16];
    const float* l3W  = (const float*)d_in[17];
    const float* l3b  = (const float*)d_in[18];
    const float* bn1g = (const float*)d_in[19];
    const float* bn1b = (const float*)d_in[20];
    const float* bn1rm= (const float*)d_in[21];
    const float* bn1rv= (const float*)d_in[22];
    const float* bn2g = (const float*)d_in[23];
    const float* bn2b = (const float*)d_in[24];
    const float* bn2rm= (const float*)d_in[25];
    const float* bn2rv= (const float*)d_in[26];
    float* out = (float*)d_out;

    // workspace layout (floats)
    float* ws = (float*)d_ws;
    size_t o = 0;
    float* h_pre = ws + o; o += 65536L * 128;    // GEMM output
    float* x_cur = ws + o; o += 52736L * 128;    // pooled x (reused every layer)
    float* z     = ws + o; o += 512L * 256;
    float* t1    = ws + o; o += 512L * 1024;
    int*   ePK   = (int*)(ws + o); o += 524288;  // packed edges (in-place remap)
    // bf16-split weights (shorts), carved from the float arena
    short* sp = (short*)(ws + o);
    short* h1s = sp;               // W1 hi  [128][160]
    short* l1s = h1s + 20480;      // W1 lo
    short* h2s = l1s + 20480;      // W2 hi  [128][128]
    short* l2s = h2s + 16384;
    short* h3s = l2s + 16384;      // W3 hi
    short* l3s = h3s + 16384;
    short* h4s = l3s + 16384;      // lin1_W hi [1024][256]
    short* l4s = h4s + 262144;     // lin1_W lo

    // ---- precompute weight splits (tiny)
    split_all<<<1232, 256, 0, stream>>>(W1, W2, W3, l1W,
        h1s, l1s, h2s, l2s, h3s, l3s, h4s, l4s);

    // ---- Layer 1: h = x @ W1  (M=65536, K=133->160)
    mfma_gemm<5,1,0><<<dim3(1,1024), 256, 0, stream>>>(
        x, h1s, l1s, h_pre, 65536, 128, 133, nullptr, nullptr, nullptr, nullptr, nullptr);
    gcn_topk<128,103,true,false,false><<<512, 1024, 0, stream>>>(
        h_pre, src, dst, ePK, b1, p1, x_cur, z);

    // ---- Layer 2: h = x2 @ W2  (M=52736, K=128)
    mfma_gemm<4,4,0><<<dim3(1,824), 256, 0, stream>>>(
        x_cur, h2s, l2s, h_pre, 52736, 128, 128, nullptr, nullptr, nullptr, nullptr, nullptr);
    gcn_topk<103,83,false,false,true><<<512, 1024, 0, stream>>>(
        h_pre, nullptr, nullptr, ePK, b2, p2, x_cur, z);

    // ---- Layer 3: h = x3 @ W3  (M=42496, K=128)
    mfma_gemm<4,4,0><<<dim3(1,664), 256, 0, stream>>>(
        x_cur, h3s, l3s, h_pre, 42496, 128, 128, nullptr, nullptr, nullptr, nullptr, nullptr);
    gcn_topk<83,67,false,true,true><<<512, 1024, 0, stream>>>(
        h_pre, nullptr, nullptr, ePK, b3, p3, nullptr, z);

    // ---- MLP head: t1 = bn1(lrelu(z @ lin1_W + b))  (M=512, N=1024, K=256)
    mfma_gemm<8,4,1><<<dim3(8,8), 256, 0, stream>>>(
        z, h4s, l4s, t1, 512, 1024, 256, l1b, bn1g, bn1b, bn1rm, bn1rv);
    mlp_tail<<<512, 256, 0, stream>>>(
        t1, l2W, l2b, bn2g, bn2b, bn2rm, bn2rv, l3W, l3b, out);
}

// Round 7
// 262.907 us; speedup vs baseline: 6.3427x; 1.1278x over previous
//
#include <hip/hip_runtime.h>

#define NEGS 0.01f
#define BNEPS 1e-5f

typedef short bf16x8 __attribute__((ext_vector_type(8)));
typedef float f32x4 __attribute__((ext_vector_type(4)));

// split fp32 -> hi/lo bf16 (RNE), a ~= hi + lo with ~2^-18 rel residual
__device__ __forceinline__ void split2(float v, short& hi, short& lo) {
    unsigned u = __float_as_uint(v);
    unsigned r = (u + 0x7FFFu + ((u >> 16) & 1u)) >> 16;
    hi = (short)r;
    float hf = __uint_as_float(r << 16);
    float l = v - hf;
    unsigned ul = __float_as_uint(l);
    lo = (short)((ul + 0x7FFFu + ((ul >> 16) & 1u)) >> 16);
}

// ---------------------------------------------------------------------------
// Precompute: split weight matrices into hi/lo bf16, TRANSPOSED to [N][K32].
// ---------------------------------------------------------------------------
__global__ __launch_bounds__(256) void split_all(
    const float* __restrict__ W1, const float* __restrict__ W2,
    const float* __restrict__ W3, const float* __restrict__ L1,
    short* __restrict__ h1, short* __restrict__ l1,
    short* __restrict__ h2, short* __restrict__ l2,
    short* __restrict__ h3, short* __restrict__ l3,
    short* __restrict__ h4, short* __restrict__ l4)
{
    int idx = blockIdx.x * 256 + threadIdx.x;
    const float* B; short *H, *L; int K, N, K32, loc;
    if (idx < 20480)      { B = W1; H = h1; L = l1; K = 133; N = 128;  K32 = 160; loc = idx; }
    else if (idx < 36864) { B = W2; H = h2; L = l2; K = 128; N = 128;  K32 = 128; loc = idx - 20480; }
    else if (idx < 53248) { B = W3; H = h3; L = l3; K = 128; N = 128;  K32 = 128; loc = idx - 36864; }
    else                  { B = L1; H = h4; L = l4; K = 256; N = 1024; K32 = 256; loc = idx - 53248; }
    int n = loc % N, k = loc / N;
    float v = (k < K) ? B[(long)k * N + n] : 0.f;
    short hi, lo; split2(v, hi, lo);
    H[(long)n * K32 + k] = hi;
    L[(long)n * K32 + k] = lo;
}

// ---------------------------------------------------------------------------
// B-resident bf16-split MFMA GEMM. B (hi+lo) staged to LDS ONCE (padded rows
// K32+8 -> 2-way-conflict b128, 16B aligned), then BARRIER-FREE K-loop:
// A global->regs (float4 if K%4==0, guarded scalar otherwise), split in-reg,
// 3-term MFMA (hh+hl+lh). Block = 128 rows x 128 cols, 4 waves x 32 rows.
// EPI 1: +bias, leaky-relu, batchnorm(eval) (MLP head).
// ---------------------------------------------------------------------------
template<int K, int K32, int EPI>
__global__ __launch_bounds__(256) void gemm_bres(
    const float* __restrict__ A, const short* __restrict__ Bh_t,
    const short* __restrict__ Bl_t, float* __restrict__ C, int N,
    const float* __restrict__ bias, const float* __restrict__ bng,
    const float* __restrict__ bnb, const float* __restrict__ bnrm,
    const float* __restrict__ bnrv)
{
    constexpr int KP = K32 + 8;          // padded LDS row (bf16 units)
    constexpr int NKS = K32 / 32;
    __shared__ short Bhs[128 * KP];
    __shared__ short Bls[128 * KP];

    const int tid = threadIdx.x;
    const int bm = blockIdx.x * 128, n0 = blockIdx.y * 128;
    const int lane = tid & 63, w = tid >> 6;
    const int lm = lane & 15, lk = (lane >> 4) * 8;

    // ---- stage B once (both halves), coalesced b128
    for (int i = tid; i < 128 * (K32 / 8); i += 256) {
        int n = i / (K32 / 8), kb = (i % (K32 / 8)) * 8;
        *(bf16x8*)&Bhs[n * KP + kb] = *(const bf16x8*)&Bh_t[(long)(n0 + n) * K32 + kb];
        *(bf16x8*)&Bls[n * KP + kb] = *(const bf16x8*)&Bl_t[(long)(n0 + n) * K32 + kb];
    }
    __syncthreads();

    const f32x4 zz = {0.f, 0.f, 0.f, 0.f};
    f32x4 acc[2][8];
#pragma unroll
    for (int i = 0; i < 2; ++i)
#pragma unroll
        for (int j = 0; j < 8; ++j) acc[i][j] = zz;

    const int r0 = bm + w * 32;
    for (int ks = 0; ks < NKS; ++ks) {
        const int k0 = ks * 32 + lk;
        bf16x8 ah[2], al[2];
#pragma unroll
        for (int mt = 0; mt < 2; ++mt) {
            const long rowb = (long)(r0 + mt * 16 + lm) * K;
            float av[8];
            if constexpr (K % 4 == 0) {
                const float4 v0 = *(const float4*)&A[rowb + k0];
                const float4 v1 = *(const float4*)&A[rowb + k0 + 4];
                av[0] = v0.x; av[1] = v0.y; av[2] = v0.z; av[3] = v0.w;
                av[4] = v1.x; av[5] = v1.y; av[6] = v1.z; av[7] = v1.w;
            } else {
#pragma unroll
                for (int j = 0; j < 8; ++j) {
                    int kk = k0 + j;
                    av[j] = (kk < K) ? A[rowb + kk] : 0.f;
                }
            }
#pragma unroll
            for (int j = 0; j < 8; ++j) {
                short h_, l_; split2(av[j], h_, l_);
                ah[mt][j] = h_; al[mt][j] = l_;
            }
        }
#pragma unroll
        for (int nt = 0; nt < 8; ++nt) {
            bf16x8 bh = *(const bf16x8*)&Bhs[(nt * 16 + lm) * KP + k0];
            bf16x8 bl = *(const bf16x8*)&Bls[(nt * 16 + lm) * KP + k0];
#pragma unroll
            for (int mt = 0; mt < 2; ++mt) {
                acc[mt][nt] = __builtin_amdgcn_mfma_f32_16x16x32_bf16(ah[mt], bh, acc[mt][nt], 0, 0, 0);
                acc[mt][nt] = __builtin_amdgcn_mfma_f32_16x16x32_bf16(ah[mt], bl, acc[mt][nt], 0, 0, 0);
                acc[mt][nt] = __builtin_amdgcn_mfma_f32_16x16x32_bf16(al[mt], bh, acc[mt][nt], 0, 0, 0);
            }
        }
    }

    // ---- epilogue: C/D map col=lane&15, row=(lane>>4)*4+reg
#pragma unroll
    for (int mt = 0; mt < 2; ++mt) {
        const int row0 = r0 + mt * 16 + (lane >> 4) * 4;
#pragma unroll
        for (int nt = 0; nt < 8; ++nt) {
            const int col = n0 + nt * 16 + lm;
            float bi = 0.f, sc_ = 1.f, rm_ = 0.f, bb_ = 0.f;
            if constexpr (EPI == 1) {
                bi = bias[col];
                sc_ = (1.0f / sqrtf(bnrv[col] + BNEPS)) * bng[col];
                rm_ = bnrm[col]; bb_ = bnb[col];
            }
#pragma unroll
            for (int r = 0; r < 4; ++r) {
                float v = acc[mt][nt][r];
                if constexpr (EPI == 1) {
                    v += bi;
                    v = v >= 0.f ? v : NEGS * v;
                    v = (v - rm_) * sc_ + bb_;
                }
                C[(long)(row0 + r) * N + col] = v;
            }
        }
    }
}

// ---------------------------------------------------------------------------
// Fused per-graph GCN+TopK, float4 datapath: thread=(4 features, half-wave=
// node). CSR gather-aggregate with b128 h-reads, 5-shfl score per node (full
// dot in one half-wave), wave0 sort, in-place packed-edge remap, float4
// readout with h_s reused as reduction scratch. ~77KB LDS -> 2 blocks/CU.
// ---------------------------------------------------------------------------
template<int NC, int KK, bool FIRST, bool LAST, bool ACCUM>
__global__ __launch_bounds__(1024, 8) void gcn_topk(
    const float* __restrict__ h_pre,     // [G*NC,128] = x @ W
    const int* __restrict__ srcIn, const int* __restrict__ dstIn, // FIRST only
    int* ePK,                            // packed edges, remapped IN PLACE
    const float* __restrict__ bias, const float* __restrict__ p,
    float* __restrict__ x_new,           // [G*KK,128]   (null when LAST)
    float* __restrict__ z)               // [G,256]
{
    __shared__ float h_s[NC][128];
    __shared__ float2 csr[1024];
    __shared__ int   head[NC];
    __shared__ float deg_s[NC], dis_s[NC], invd_s[NC];
    __shared__ float sc[128];
    __shared__ int   id[128];
    __shared__ float gate[KK];
    __shared__ float b_s[128], p_s[128];
    __shared__ int   remap_l[NC];
    __shared__ float pnorm;

    const int g = blockIdx.x, tid = threadIdx.x, lane = tid & 63;
    const int f4 = (tid & 31) * 4;       // feature base
    const int grp = tid >> 5;            // half-wave id 0..31
    const float NINF = -__builtin_inff();
    constexpr int NIT4 = (NC + 31) / 32;

    // ---- edge in registers (slot g*1024+tid owned by this thread)
    int es_r, ed_r; bool live;
    {
        int eg = g * 1024 + tid;
        if (FIRST) { es_r = srcIn[eg] & 127; ed_r = dstIn[eg] & 127; live = true; }
        else       { int pk = ePK[eg]; es_r = pk & 127; ed_r = (pk >> 7) & 127; live = (pk >> 14) != 0; }
    }

    // ---- stage h tile (float4) + init
    {
        const float4* hp = (const float4*)(h_pre + (long)g * NC * 128);
        float4* h4 = (float4*)&h_s[0][0];
        for (int i = tid; i < NC * 32; i += 1024) h4[i] = hp[i];
    }
    if (tid < 128) { b_s[tid] = bias[tid]; p_s[tid] = p[tid]; }
    for (int i = tid; i < NC; i += 1024) { deg_s[i] = 1.f; head[i] = 0; }
    __syncthreads();

    // ---- ||p|| (wave0) + degree/count histograms
    if (tid < 64) {
        float s = p_s[tid] * p_s[tid] + p_s[tid + 64] * p_s[tid + 64];
#pragma unroll
        for (int o = 32; o; o >>= 1) s += __shfl_xor(s, o, 64);
        if (tid == 0) pnorm = sqrtf(s);
    }
    if (live) {
        atomicAdd(&deg_s[ed_r], 1.0f);
        atomicAdd(&head[ed_r], 1);
    }
    __syncthreads();

    for (int i = tid; i < NC; i += 1024) {
        float d = deg_s[i];
        dis_s[i] = 1.0f / sqrtf(d);
        invd_s[i] = 1.0f / d;
    }
    // ---- exclusive scan of counts -> head (wave0)
    if (tid < 64) {
        int c0 = head[tid];
        int c1 = (tid + 64 < NC) ? head[tid + 64] : 0;
        int s0 = c0, s1 = c1;
#pragma unroll
        for (int o = 1; o < 64; o <<= 1) { int t = __shfl_up(s0, o, 64); if (lane >= o) s0 += t; }
        int tot0 = __shfl(s0, 63, 64);
#pragma unroll
        for (int o = 1; o < 64; o <<= 1) { int t = __shfl_up(s1, o, 64); if (lane >= o) s1 += t; }
        s1 += tot0;
        head[tid] = s0 - c0;
        if (tid + 64 < NC) head[tid + 64] = s1 - c1;
    }
    __syncthreads();

    // ---- CSR place (head becomes per-node END offset afterwards)
    if (live) {
        int slot = atomicAdd(&head[ed_r], 1);
        csr[slot] = make_float2(__int_as_float(es_r), dis_s[es_r] * dis_s[ed_r]);
    }
    __syncthreads();

    // ---- float4 gather-aggregate + act (regs) + full-dot score per node
    const float4 p4 = *(const float4*)&p_s[f4];
    const float4 b4 = *(const float4*)&b_s[f4];
    float4 va[NIT4];
#pragma unroll
    for (int i = 0; i < NIT4; ++i) {
        int nd = grp + i * 32;
        if ((NC & 31) == 0 || nd < NC) {
            int kb = nd ? head[nd - 1] : 0;
            int ke = head[nd];
            float4 acc = make_float4(0.f, 0.f, 0.f, 0.f);
            for (int k = kb; k < ke; ++k) {
                float2 rec = csr[k];
                const float4 hv = *(const float4*)&h_s[__float_as_int(rec.x)][f4];
                acc.x = fmaf(hv.x, rec.y, acc.x);
                acc.y = fmaf(hv.y, rec.y, acc.y);
                acc.z = fmaf(hv.z, rec.y, acc.z);
                acc.w = fmaf(hv.w, rec.y, acc.w);
            }
            const float4 h0 = *(const float4*)&h_s[nd][f4];
            const float iv = invd_s[nd];
            float4 v;
            v.x = acc.x + h0.x * iv + b4.x;
            v.y = acc.y + h0.y * iv + b4.y;
            v.z = acc.z + h0.z * iv + b4.z;
            v.w = acc.w + h0.w * iv + b4.w;
            v.x = v.x >= 0.f ? v.x : NEGS * v.x;
            v.y = v.y >= 0.f ? v.y : NEGS * v.y;
            v.z = v.z >= 0.f ? v.z : NEGS * v.z;
            v.w = v.w >= 0.f ? v.w : NEGS * v.w;
            va[i] = v;
            float ps = v.x * p4.x + v.y * p4.y + v.z * p4.z + v.w * p4.w;
            ps += __shfl_xor(ps, 16, 64);
            ps += __shfl_xor(ps, 8, 64);
            ps += __shfl_xor(ps, 4, 64);
            ps += __shfl_xor(ps, 2, 64);
            ps += __shfl_xor(ps, 1, 64);
            if ((tid & 31) == 0) sc[nd] = ps;
        }
    }
    __syncthreads();   // all h_s reads + sc writes done

    // ---- overwrite h_s with activated values (LDS-resident)
#pragma unroll
    for (int i = 0; i < NIT4; ++i) {
        int nd = grp + i * 32;
        if ((NC & 31) == 0 || nd < NC) *(float4*)&h_s[nd][f4] = va[i];
    }
    __syncthreads();

    // ---- finalize scores
    if (tid < 128) {
        if (tid < NC) { sc[tid] = sc[tid] / pnorm; id[tid] = tid; }
        else          { sc[tid] = NINF; id[tid] = 0x7fffffff; }
    }
    __syncthreads();

    // ---- bitonic sort (128) on wave 0, lockstep
    if (tid < 64) {
        for (int size = 2; size <= 128; size <<= 1) {
            for (int stride = size >> 1; stride > 0; stride >>= 1) {
                int i = 2 * stride * (tid / stride) + (tid % stride);
                int j = i + stride;
                float si_ = sc[i], sj_ = sc[j];
                int ii = id[i], ij = id[j];
                bool iFirst = (si_ > sj_) || (si_ == sj_ && ii < ij);
                bool descRegion = ((i & size) == 0);
                bool doSwap = descRegion ? !iFirst : iFirst;
                if (doSwap) { sc[i] = sj_; sc[j] = si_; id[i] = ij; id[j] = ii; }
                __asm__ volatile("" ::: "memory");
            }
        }
    }
    __syncthreads();

    // ---- gates + remap table
    for (int j = tid; j < KK; j += 1024) gate[j] = tanhf(sc[j]);
    if constexpr (!LAST) {
        for (int i = tid; i < NC; i += 1024) remap_l[i] = -1;
    }
    __syncthreads();
    if constexpr (!LAST) {
        for (int j = tid; j < KK; j += 1024) remap_l[id[j]] = j;
    }
    __syncthreads();

    // ---- in-place packed edge remap
    if constexpr (!LAST) {
        int s2 = remap_l[es_r], d2 = remap_l[ed_r];
        bool ok = (s2 >= 0) && (d2 >= 0);
        int lv = (live && ok) ? 1 : 0;
        ePK[g * 1024 + tid] = (ok ? s2 : 0) | ((ok ? d2 : 0) << 7) | (lv << 14);
    }

    // ---- float4 gather + gate + x_new + readout (h_s reused as scratch)
    {
        const int jj = tid >> 5;             // 0..31
        float4 rmx = make_float4(NINF, NINF, NINF, NINF);
        float4 rsm = make_float4(0.f, 0.f, 0.f, 0.f);
        for (int j = jj; j < KK; j += 32) {
            const float gt = gate[j];
            const float4 hv = *(const float4*)&h_s[id[j]][f4];
            float4 v;
            v.x = hv.x * gt; v.y = hv.y * gt; v.z = hv.z * gt; v.w = hv.w * gt;
            if constexpr (!LAST) *(float4*)&x_new[((long)g * KK + j) * 128 + f4] = v;
            rmx.x = fmaxf(rmx.x, v.x); rmx.y = fmaxf(rmx.y, v.y);
            rmx.z = fmaxf(rmx.z, v.z); rmx.w = fmaxf(rmx.w, v.w);
            rsm.x += v.x; rsm.y += v.y; rsm.z += v.z; rsm.w += v.w;
        }
        // combine jj pairs (lane <-> lane+32)
        rmx.x = fmaxf(rmx.x, __shfl_xor(rmx.x, 32, 64));
        rmx.y = fmaxf(rmx.y, __shfl_xor(rmx.y, 32, 64));
        rmx.z = fmaxf(rmx.z, __shfl_xor(rmx.z, 32, 64));
        rmx.w = fmaxf(rmx.w, __shfl_xor(rmx.w, 32, 64));
        rsm.x += __shfl_xor(rsm.x, 32, 64);
        rsm.y += __shfl_xor(rsm.y, 32, 64);
        rsm.z += __shfl_xor(rsm.z, 32, 64);
        rsm.w += __shfl_xor(rsm.w, 32, 64);
        __syncthreads();                     // all h_s gather reads done
        if (lane < 32) {
            const int w = tid >> 6;          // 0..15
            *(float4*)&h_s[w][f4] = rmx;
            *(float4*)&h_s[16 + w][f4] = rsm;
        }
    }
    __syncthreads();

    if (tid < 128) {
        float m = h_s[0][tid], s = h_s[16][tid];
#pragma unroll
        for (int q = 1; q < 16; ++q) { m = fmaxf(m, h_s[q][tid]); s += h_s[16 + q][tid]; }
        float mean = s / (float)KK;
        if constexpr (ACCUM) {
            z[g * 256 + tid] += m;
            z[g * 256 + 128 + tid] += mean;
        } else {
            z[g * 256 + tid] = m;
            z[g * 256 + 128 + tid] = mean;
        }
    }
}

// ---------------------------------------------------------------------------
// MLP tail per row: lin2 (1024->64) + lrelu + bn2, lin3 (64->2) + bias.
// ---------------------------------------------------------------------------
__global__ __launch_bounds__(256) void mlp_tail(
    const float* __restrict__ t1,
    const float* __restrict__ W2, const float* __restrict__ b2v,
    const float* __restrict__ g2, const float* __restrict__ bb2,
    const float* __restrict__ rm2, const float* __restrict__ rv2,
    const float* __restrict__ W3, const float* __restrict__ b3v,
    float* __restrict__ out)
{
    __shared__ float t1s[1024];
    __shared__ float part[4][64];
    __shared__ float t2s[64];
    const int row = blockIdx.x, tid = threadIdx.x;

    for (int i = tid; i < 1024; i += 256) t1s[i] = t1[(long)row * 1024 + i];
    __syncthreads();

    int c = tid & 63, seg = tid >> 6;
    float s = 0.f;
    for (int k = seg * 256; k < seg * 256 + 256; ++k)
        s = fmaf(t1s[k], W2[k * 64 + c], s);
    part[seg][c] = s;
    __syncthreads();

    if (tid < 64) {
        float v = part[0][c] + part[1][c] + part[2][c] + part[3][c] + b2v[c];
        v = v >= 0.f ? v : NEGS * v;
        v = (v - rm2[c]) * (1.0f / sqrtf(rv2[c] + BNEPS)) * g2[c] + bb2[c];
        t2s[c] = v;
    }
    __syncthreads();

    if (tid < 128) {
        int cc = tid >> 6, k = tid & 63;
        float prod = t2s[k] * W3[k * 2 + cc];
#pragma unroll
        for (int o = 32; o; o >>= 1) prod += __shfl_xor(prod, o, 64);
        if (k == 0) out[row * 2 + cc] = prod + b3v[cc];
    }
}

// ---------------------------------------------------------------------------
extern "C" void kernel_launch(void* const* d_in, const int* in_sizes, int n_in,
                              void* d_out, int out_size, void* d_ws, size_t ws_size,
                              hipStream_t stream)
{
    const float* x    = (const float*)d_in[0];
    const int*   src  = (const int*)d_in[1];
    const int*   dst  = (const int*)d_in[2];
    const float* W1   = (const float*)d_in[4];
    const float* b1   = (const float*)d_in[5];
    const float* W2   = (const float*)d_in[6];
    const float* b2   = (const float*)d_in[7];
    const float* W3   = (const float*)d_in[8];
    const float* b3   = (const float*)d_in[9];
    const float* p1   = (const float*)d_in[10];
    const float* p2   = (const float*)d_in[11];
    const float* p3   = (const float*)d_in[12];
    const float* l1W  = (const float*)d_in[13];
    const float* l1b  = (const float*)d_in[14];
    const float* l2W  = (const float*)d_in[15];
    const float* l2b  = (const float*)d_in[16];
    const float* l3W  = (const float*)d_in[17];
    const float* l3b  = (const float*)d_in[18];
    const float* bn1g = (const float*)d_in[19];
    const float* bn1b = (const float*)d_in[20];
    const float* bn1rm= (const float*)d_in[21];
    const float* bn1rv= (const float*)d_in[22];
    const float* bn2g = (const float*)d_in[23];
    const float* bn2b = (const float*)d_in[24];
    const float* bn2rm= (const float*)d_in[25];
    const float* bn2rv= (const float*)d_in[26];
    float* out = (float*)d_out;

    // workspace layout (floats)
    float* ws = (float*)d_ws;
    size_t o = 0;
    float* h_pre = ws + o; o += 65536L * 128;
    float* x_cur = ws + o; o += 52736L * 128;
    float* z     = ws + o; o += 512L * 256;
    float* t1    = ws + o; o += 512L * 1024;
    int*   ePK   = (int*)(ws + o); o += 524288;
    short* sp = (short*)(ws + o);
    short* h1s = sp;               // W1 hi  [128][160]
    short* l1s = h1s + 20480;
    short* h2s = l1s + 20480;      // W2 hi  [128][128]
    short* l2s = h2s + 16384;
    short* h3s = l2s + 16384;      // W3 hi
    short* l3s = h3s + 16384;
    short* h4s = l3s + 16384;      // lin1_W hi [1024][256]
    short* l4s = h4s + 262144;

    // ---- precompute weight splits
    split_all<<<1232, 256, 0, stream>>>(W1, W2, W3, l1W,
        h1s, l1s, h2s, l2s, h3s, l3s, h4s, l4s);

    // ---- Layer 1: h = x @ W1  (M=65536, K=133->160)
    gemm_bres<133,160,0><<<dim3(512,1), 256, 0, stream>>>(
        x, h1s, l1s, h_pre, 128, nullptr, nullptr, nullptr, nullptr, nullptr);
    gcn_topk<128,103,true,false,false><<<512, 1024, 0, stream>>>(
        h_pre, src, dst, ePK, b1, p1, x_cur, z);

    // ---- Layer 2: h = x2 @ W2  (M=52736, K=128)
    gemm_bres<128,128,0><<<dim3(412,1), 256, 0, stream>>>(
        x_cur, h2s, l2s, h_pre, 128, nullptr, nullptr, nullptr, nullptr, nullptr);
    gcn_topk<103,83,false,false,true><<<512, 1024, 0, stream>>>(
        h_pre, nullptr, nullptr, ePK, b2, p2, x_cur, z);

    // ---- Layer 3: h = x3 @ W3  (M=42496, K=128)
    gemm_bres<128,128,0><<<dim3(332,1), 256, 0, stream>>>(
        x_cur, h3s, l3s, h_pre, 128, nullptr, nullptr, nullptr, nullptr, nullptr);
    gcn_topk<83,67,false,true,true><<<512, 1024, 0, stream>>>(
        h_pre, nullptr, nullptr, ePK, b3, p3, nullptr, z);

    // ---- MLP head: t1 = bn1(lrelu(z @ lin1_W + b))  (M=512, N=1024, K=256)
    gemm_bres<256,256,1><<<dim3(4,8), 256, 0, stream>>>(
        z, h4s, l4s, t1, 1024, l1b, bn1g, bn1b, bn1rm, bn1rv);
    mlp_tail<<<512, 256, 0, stream>>>(
        t1, l2W, l2b, bn2g, bn2b, bn2rm, bn2rv, l3W, l3b, out);
}